// Round 5
// baseline (3548.449 us; speedup 1.0000x reference)
//
#include <hip/hip_runtime.h>
#include <math.h>

#define D_MODEL   2048
#define D_INNER   4096
#define XBC_DIM   4224
#define D_IN_PROJ 8384
#define N_ZX      8320      // z (4096) + xBC (4224); dt_raw cols skipped
#define NH    64
#define HD    64
#define DS    64
#define LCH   256
#define NCH   8
#define LSEQ  2048
#define TTOK  4096
#define EPS_R 1.1920929e-07f

typedef unsigned short u16;
typedef unsigned int   u32;

__device__ __forceinline__ float bf2f(u16 u) {
    u32 i = ((u32)u) << 16; float f; __builtin_memcpy(&f, &i, 4); return f;
}
__device__ __forceinline__ u16 f2bf(float f) {
    u32 i; __builtin_memcpy(&i, &f, 4);
    u32 r = (i + 0x7FFFu + ((i >> 16) & 1u)) >> 16;
    return (u16)r;
}

template<bool CF32>
__device__ __forceinline__ float4 cbuf_ld4(const void* c, size_t idx) {
    if constexpr (CF32) return *(const float4*)((const float*)c + idx);
    ushort4 u = *(const ushort4*)((const u16*)c + idx);
    return make_float4(bf2f(u.x), bf2f(u.y), bf2f(u.z), bf2f(u.w));
}
template<bool CF32>
__device__ __forceinline__ float cbuf_ld1(const void* c, size_t idx) {
    if constexpr (CF32) return ((const float*)c)[idx];
    return bf2f(((const u16*)c)[idx]);
}

// ---- GEMM1: [zf f32 | cbuf] = x[T][2048] @ w_in[0:8320]^T ---------------
template<int BM, int BN, int BK, bool CF32>
__global__ __launch_bounds__(256) void gemm_in(const float* __restrict__ A,
                                               const float* __restrict__ B,
                                               float* __restrict__ zf,
                                               void* __restrict__ cbuf) {
    __shared__ float As[BK][BM + 4];
    __shared__ float Bs[BK][BN + 4];
    const int tid = threadIdx.x;
    const int row0 = blockIdx.y * BM, col0 = blockIdx.x * BN;
    const int tx = tid & 15, ty = tid >> 4;
    float acc[8][8];
    #pragma unroll
    for (int i = 0; i < 8; ++i)
        #pragma unroll
        for (int j = 0; j < 8; ++j) acc[i][j] = 0.f;

    const int lr = tid >> 2, lc = (tid & 3) * 4;
    for (int k0 = 0; k0 < D_MODEL; k0 += BK) {
        #pragma unroll
        for (int i = 0; i < BM / 64; ++i) {
            int r = lr + i * 64;
            float4 v = *(const float4*)(A + (size_t)(row0 + r) * D_MODEL + k0 + lc);
            As[lc + 0][r] = v.x; As[lc + 1][r] = v.y;
            As[lc + 2][r] = v.z; As[lc + 3][r] = v.w;
        }
        #pragma unroll
        for (int i = 0; i < BN / 64; ++i) {
            int r = lr + i * 64;
            float4 v = *(const float4*)(B + (size_t)(col0 + r) * D_MODEL + k0 + lc);
            Bs[lc + 0][r] = v.x; Bs[lc + 1][r] = v.y;
            Bs[lc + 2][r] = v.z; Bs[lc + 3][r] = v.w;
        }
        __syncthreads();
        #pragma unroll
        for (int kk = 0; kk < BK; ++kk) {
            float a[8], b[8];
            *(float4*)&a[0] = *(const float4*)&As[kk][ty * 8];
            *(float4*)&a[4] = *(const float4*)&As[kk][ty * 8 + 4];
            *(float4*)&b[0] = *(const float4*)&Bs[kk][tx * 8];
            *(float4*)&b[4] = *(const float4*)&Bs[kk][tx * 8 + 4];
            #pragma unroll
            for (int i = 0; i < 8; ++i)
                #pragma unroll
                for (int j = 0; j < 8; ++j) acc[i][j] += a[i] * b[j];
        }
        __syncthreads();
    }
    #pragma unroll
    for (int i = 0; i < 8; ++i) {
        int r = row0 + ty * 8 + i;
        int cbase = col0 + tx * 8;
        if (col0 < D_INNER) {              // z block -> f32
            float* crow = zf + (size_t)r * D_INNER + cbase;
            *(float4*)(crow)     = make_float4(acc[i][0], acc[i][1], acc[i][2], acc[i][3]);
            *(float4*)(crow + 4) = make_float4(acc[i][4], acc[i][5], acc[i][6], acc[i][7]);
        } else {                           // conv-input block
            int cc = cbase - D_INNER;
            if constexpr (CF32) {
                float* crow = (float*)cbuf + (size_t)r * XBC_DIM + cc;
                *(float4*)(crow)     = make_float4(acc[i][0], acc[i][1], acc[i][2], acc[i][3]);
                *(float4*)(crow + 4) = make_float4(acc[i][4], acc[i][5], acc[i][6], acc[i][7]);
            } else {
                u16* crow = (u16*)cbuf + (size_t)r * XBC_DIM + cc;
                *(ushort4*)(crow)     = make_ushort4(f2bf(acc[i][0]), f2bf(acc[i][1]),
                                                     f2bf(acc[i][2]), f2bf(acc[i][3]));
                *(ushort4*)(crow + 4) = make_ushort4(f2bf(acc[i][4]), f2bf(acc[i][5]),
                                                     f2bf(acc[i][6]), f2bf(acc[i][7]));
            }
        }
    }
}

// ---- GEMM2: out[T][2048] = (u * rstd[row] * nw[k]) @ w_out^T ------------
template<int BM, int BN, int BK>
__global__ __launch_bounds__(256) void gemm_out(const float* __restrict__ U,
                                                const float* __restrict__ B,
                                                float* __restrict__ C,
                                                const float* __restrict__ rstd,
                                                const float* __restrict__ nw) {
    __shared__ float As[BK][BM + 4];
    __shared__ float Bs[BK][BN + 4];
    const int tid = threadIdx.x;
    const int row0 = blockIdx.y * BM, col0 = blockIdx.x * BN;
    const int tx = tid & 15, ty = tid >> 4;
    float acc[8][8];
    #pragma unroll
    for (int i = 0; i < 8; ++i)
        #pragma unroll
        for (int j = 0; j < 8; ++j) acc[i][j] = 0.f;

    const int lr = tid >> 2, lc = (tid & 3) * 4;
    for (int k0 = 0; k0 < D_INNER; k0 += BK) {
        #pragma unroll
        for (int i = 0; i < BM / 64; ++i) {
            int r = lr + i * 64;
            float4 v = *(const float4*)(U + (size_t)(row0 + r) * D_INNER + k0 + lc);
            float s = rstd[row0 + r];
            float4 w4 = *(const float4*)(nw + k0 + lc);
            v.x *= s * w4.x; v.y *= s * w4.y; v.z *= s * w4.z; v.w *= s * w4.w;
            As[lc + 0][r] = v.x; As[lc + 1][r] = v.y;
            As[lc + 2][r] = v.z; As[lc + 3][r] = v.w;
        }
        #pragma unroll
        for (int i = 0; i < BN / 64; ++i) {
            int r = lr + i * 64;
            float4 v = *(const float4*)(B + (size_t)(col0 + r) * D_INNER + k0 + lc);
            Bs[lc + 0][r] = v.x; Bs[lc + 1][r] = v.y;
            Bs[lc + 2][r] = v.z; Bs[lc + 3][r] = v.w;
        }
        __syncthreads();
        #pragma unroll
        for (int kk = 0; kk < BK; ++kk) {
            float a[8], b[8];
            *(float4*)&a[0] = *(const float4*)&As[kk][ty * 8];
            *(float4*)&a[4] = *(const float4*)&As[kk][ty * 8 + 4];
            *(float4*)&b[0] = *(const float4*)&Bs[kk][tx * 8];
            *(float4*)&b[4] = *(const float4*)&Bs[kk][tx * 8 + 4];
            #pragma unroll
            for (int i = 0; i < 8; ++i)
                #pragma unroll
                for (int j = 0; j < 8; ++j) acc[i][j] += a[i] * b[j];
        }
        __syncthreads();
    }
    #pragma unroll
    for (int i = 0; i < 8; ++i) {
        int r = row0 + ty * 8 + i;
        int cbase = col0 + tx * 8;
        float* crow = C + (size_t)r * D_MODEL + cbase;
        *(float4*)(crow)     = make_float4(acc[i][0], acc[i][1], acc[i][2], acc[i][3]);
        *(float4*)(crow + 4) = make_float4(acc[i][4], acc[i][5], acc[i][6], acc[i][7]);
    }
}

// ----- dt projection in pure f32 -----------------------------------------
__global__ __launch_bounds__(256) void dtproj_kernel(const float* __restrict__ x,
                                                     const float* __restrict__ w_in,
                                                     const float* __restrict__ dt_bias,
                                                     float* __restrict__ dt_buf) {
    __shared__ float Xs[16][64];
    __shared__ float Ws[64][65];
    int tid = threadIdx.x;
    int t0 = blockIdx.x * 16;
    int h = tid & 63, trow = tid >> 6;
    float acc[4] = {0.f, 0.f, 0.f, 0.f};
    const float* wdt = w_in + (size_t)(D_INNER + XBC_DIM) * D_MODEL;

    for (int k0 = 0; k0 < D_MODEL; k0 += 64) {
        __syncthreads();
        {
            int r = tid >> 4, c4 = (tid & 15) * 4;
            *(float4*)&Xs[r][c4] = *(const float4*)(x + (size_t)(t0 + r) * D_MODEL + k0 + c4);
        }
        #pragma unroll
        for (int i = 0; i < 4; ++i) {
            int ff = tid + i * 256;
            int r = ff >> 4, c4 = (ff & 15) * 4;
            float4 v = *(const float4*)(wdt + (size_t)r * D_MODEL + k0 + c4);
            Ws[r][c4 + 0] = v.x; Ws[r][c4 + 1] = v.y;
            Ws[r][c4 + 2] = v.z; Ws[r][c4 + 3] = v.w;
        }
        __syncthreads();
        #pragma unroll 16
        for (int k = 0; k < 64; ++k) {
            float wv = Ws[h][k];
            #pragma unroll
            for (int i = 0; i < 4; ++i)
                acc[i] += Xs[trow + i * 4][k] * wv;
        }
    }
    float bias = dt_bias[h];
    #pragma unroll
    for (int i = 0; i < 4; ++i) {
        float xv = acc[i] + bias;
        float sp = (xv > 20.f) ? xv : log1pf(expf(xv));
        dt_buf[(size_t)(t0 + trow + i * 4) * 64 + h] = sp;
    }
}

// ------------- per-(b,h) chunk-local inclusive cumsum of a=A*dt ----------
__global__ __launch_bounds__(256) void scan_kernel(const float* __restrict__ dt_buf,
                                                   const float* __restrict__ A_log,
                                                   float* __restrict__ acs) {
    int b = blockIdx.x >> 6, h = blockIdx.x & 63;
    float Ah = -expf(A_log[h]);
    __shared__ float s[256];
    int tid = threadIdx.x;
    for (int c = 0; c < NCH; ++c) {
        int t = b * LSEQ + c * LCH + tid;
        float a = Ah * dt_buf[t * 64 + h];
        s[tid] = a;
        __syncthreads();
        for (int off = 1; off < 256; off <<= 1) {
            float v = (tid >= off) ? s[tid - off] : 0.f;
            __syncthreads();
            s[tid] += v;
            __syncthreads();
        }
        acs[(size_t)blockIdx.x * LSEQ + c * LCH + tid] = s[tid];
        __syncthreads();
    }
}

// ---- convolved B/C (128 channels) in f32 --------------------------------
template<bool CF32>
__global__ __launch_bounds__(128) void bcconv_kernel(const void* __restrict__ cbuf,
                                                     const float* __restrict__ cw,
                                                     const float* __restrict__ cb,
                                                     float* __restrict__ bc) {
    int chl = threadIdx.x;            // 0..127
    int t = blockIdx.x;
    int b = t >> 11, lp = t & 2047;
    int ch = D_INNER + chl;           // conv channel 4096..4223
    float acc = cb[ch];
    #pragma unroll
    for (int j = 0; j < 4; ++j) {
        int lj = lp - 3 + j;
        if (lj >= 0)
            acc += cw[ch * 4 + j] * cbuf_ld1<CF32>(cbuf, (size_t)(b * LSEQ + lj) * XBC_DIM + ch);
    }
    bc[(size_t)t * 128 + chl] = acc / (1.f + expf(-acc));
}

// conv-fused staging of one 64x64 X tile (unscaled silu(conv)) ------------
template<bool CF32>
__device__ __forceinline__ void stage_x_tile(const void* cbuf, const float* cw,
                                             const float* cb, int b, int lp0,
                                             int h, int tid, float Xt[64][64]) {
    #pragma unroll
    for (int i = 0; i < 4; ++i) {
        int ff = tid + i * 256;
        int r = ff >> 4, c4 = ff & 15;
        int lp = lp0 + r;
        int ch0 = h * HD + c4 * 4;
        float tp[4][4];
        #pragma unroll
        for (int k = 0; k < 4; ++k)
            *(float4*)tp[k] = *(const float4*)(cw + (size_t)(ch0 + k) * 4);
        float a0 = cb[ch0], a1 = cb[ch0 + 1], a2 = cb[ch0 + 2], a3 = cb[ch0 + 3];
        #pragma unroll
        for (int j = 0; j < 4; ++j) {
            int lj = lp - 3 + j;
            if (lj >= 0) {
                float4 v = cbuf_ld4<CF32>(cbuf, (size_t)(b * LSEQ + lj) * XBC_DIM + ch0);
                a0 += tp[0][j] * v.x; a1 += tp[1][j] * v.y;
                a2 += tp[2][j] * v.z; a3 += tp[3][j] * v.w;
            }
        }
        Xt[r][c4 * 4 + 0] = a0 / (1.f + expf(-a0));
        Xt[r][c4 * 4 + 1] = a1 / (1.f + expf(-a1));
        Xt[r][c4 * 4 + 2] = a2 / (1.f + expf(-a2));
        Xt[r][c4 * 4 + 3] = a3 / (1.f + expf(-a3));
    }
}

// ----- chunk states: states[p][n] = sum_s B[s,n]·dec[s]·dt[s]·X[s,p] -----
template<bool CF32>
__global__ __launch_bounds__(256) void chunkstate_kernel(const void* __restrict__ cbuf,
                                                         const float* __restrict__ bc,
                                                         const float* __restrict__ cw,
                                                         const float* __restrict__ cb,
                                                         const float* __restrict__ dt_buf,
                                                         const float* __restrict__ acs,
                                                         float* __restrict__ states) {
    int h = blockIdx.x & 63;
    int c = (blockIdx.x >> 6) & 7;
    int b = blockIdx.x >> 9;
    int tbase = b * LSEQ + c * LCH;
    const float* acs_blk = acs + (size_t)(b * 64 + h) * LSEQ + c * LCH;
    float acs_last = acs_blk[LCH - 1];

    __shared__ float Bt[64][64];
    __shared__ float Xt[64][64];
    __shared__ float dec[64];

    float4 acc4[4];
    #pragma unroll
    for (int i = 0; i < 4; ++i) acc4[i] = make_float4(0.f, 0.f, 0.f, 0.f);
    int tid = threadIdx.x;
    int p = tid & 63, n0 = (tid >> 6) * 16;

    for (int s0 = 0; s0 < LCH; s0 += 64) {
        __syncthreads();
        #pragma unroll
        for (int i = 0; i < 4; ++i) {
            int ff = tid + i * 256;
            int r = ff >> 4, c4 = ff & 15;
            *(float4*)&Bt[r][c4 * 4] =
                *(const float4*)(bc + (size_t)(tbase + s0 + r) * 128 + c4 * 4);
        }
        stage_x_tile<CF32>(cbuf, cw, cb, b, c * LCH + s0, h, tid, Xt);
        if (tid < 64)
            dec[tid] = expf(acs_last - acs_blk[s0 + tid])
                     * dt_buf[(size_t)(tbase + s0 + tid) * 64 + h];
        __syncthreads();

        for (int si = 0; si < 64; ++si) {
            float xv = Xt[si][p] * dec[si];
            const float4* bp = (const float4*)&Bt[si][n0];
            #pragma unroll
            for (int i = 0; i < 4; ++i) {
                float4 bv = bp[i];
                acc4[i].x += xv * bv.x; acc4[i].y += xv * bv.y;
                acc4[i].z += xv * bv.z; acc4[i].w += xv * bv.w;
            }
        }
    }
    float4* sp = (float4*)(states + (size_t)blockIdx.x * 4096 + p * 64 + n0);
    #pragma unroll
    for (int i = 0; i < 4; ++i) sp[i] = acc4[i];
}

// ----- inter-chunk recurrence per (b,h); in-place ------------------------
__global__ __launch_bounds__(256) void chunkscan_kernel(const float* __restrict__ acs,
                                                        float* __restrict__ states) {
    int b = blockIdx.x >> 6, h = blockIdx.x & 63;
    int tid = threadIdx.x;
    float4 S4[4];
    #pragma unroll
    for (int i = 0; i < 4; ++i) S4[i] = make_float4(0.f, 0.f, 0.f, 0.f);
    const float* acs_blk = acs + (size_t)blockIdx.x * LSEQ;
    for (int c = 0; c < NCH; ++c) {
        float d = expf(acs_blk[c * LCH + LCH - 1]);
        float4* sp = (float4*)(states + ((size_t)(b * NCH + c) * NH + h) * 4096 + tid * 16);
        float4 t4[4];
        #pragma unroll
        for (int i = 0; i < 4; ++i) t4[i] = sp[i];
        #pragma unroll
        for (int i = 0; i < 4; ++i) sp[i] = S4[i];
        #pragma unroll
        for (int i = 0; i < 4; ++i) {
            S4[i].x = d * S4[i].x + t4[i].x;
            S4[i].y = d * S4[i].y + t4[i].y;
            S4[i].z = d * S4[i].z + t4[i].z;
            S4[i].w = d * S4[i].w + t4[i].w;
        }
    }
}

// ----- merged Y + gate: u = z*silu(Y_off+Y_diag+xs*D), u in-place over z -
template<bool CF32>
__global__ __launch_bounds__(256) void ymerged_kernel(const void* __restrict__ cbuf,
                                                      const float* __restrict__ bc,
                                                      const float* __restrict__ cw,
                                                      const float* __restrict__ cb,
                                                      float* __restrict__ zf,
                                                      const float* __restrict__ dt_buf,
                                                      const float* __restrict__ acs,
                                                      const float* __restrict__ states,
                                                      const float* __restrict__ D_param,
                                                      float* __restrict__ usq) {
    int h = blockIdx.x & 63;
    int c = (blockIdx.x >> 6) & 7;
    int b = blockIdx.x >> 9;
    int l = threadIdx.x;
    int tid = l;
    int tbase = b * LSEQ + c * LCH;
    int tl = tbase + l;
    const float* acs_blk = acs + (size_t)(b * 64 + h) * LSEQ + c * LCH;
    float acs_l = acs_blk[l];
    float Dp = D_param[h];

    __shared__ float Slds[4096];
    __shared__ float Bt[64][64];
    __shared__ float Xt[64][64];
    __shared__ float acs_s[64];
    __shared__ float dts[64];

    const float4* sp = (const float4*)(states + (size_t)blockIdx.x * 4096);
    for (int i = tid; i < 1024; i += 256) ((float4*)Slds)[i] = sp[i];

    // convolved C row (f32, from bc buffer cols 64..127)
    float Cr[64];
    #pragma unroll
    for (int i = 0; i < 16; ++i) {
        float4 v = *(const float4*)(bc + (size_t)tl * 128 + 64 + i * 4);
        Cr[i * 4 + 0] = v.x; Cr[i * 4 + 1] = v.y;
        Cr[i * 4 + 2] = v.z; Cr[i * 4 + 3] = v.w;
    }
    __syncthreads();

    // Y_off
    float e = expf(acs_l);
    float yacc[64];
    #pragma unroll 4
    for (int p = 0; p < HD; ++p) {
        float dot = 0.f;
        const float4* srow = (const float4*)&Slds[p * 64];
        #pragma unroll
        for (int i = 0; i < 16; ++i) {
            float4 sv = srow[i];
            dot += Cr[i * 4 + 0] * sv.x + Cr[i * 4 + 1] * sv.y
                 + Cr[i * 4 + 2] * sv.z + Cr[i * 4 + 3] * sv.w;
        }
        yacc[p] = e * dot;
    }

    // Y_diag tiles + D-term capture
    for (int s0 = 0; s0 < LCH; s0 += 64) {
        __syncthreads();
        #pragma unroll
        for (int i = 0; i < 4; ++i) {
            int ff = tid + i * 256;
            int r = ff >> 4, c4 = ff & 15;
            *(float4*)&Bt[r][c4 * 4] =
                *(const float4*)(bc + (size_t)(tbase + s0 + r) * 128 + c4 * 4);
        }
        stage_x_tile<CF32>(cbuf, cw, cb, b, c * LCH + s0, h, tid, Xt);
        if (tid < 64) {
            acs_s[tid] = acs_blk[s0 + tid];
            dts[tid] = dt_buf[(size_t)(tbase + s0 + tid) * 64 + h];
        }
        __syncthreads();

        if (l >= s0 && l < s0 + 64) {       // xs*D from resident tile
            const float* xr = &Xt[l - s0][0];
            #pragma unroll
            for (int p = 0; p < 64; ++p) yacc[p] += xr[p] * Dp;
        }

        int smax = l - s0;
        int slim = (smax >= 63) ? 64 : (smax + 1);
        for (int si = 0; si < slim; ++si) {
            float dot = 0.f;
            const float4* bp = (const float4*)&Bt[si][0];
            #pragma unroll
            for (int i = 0; i < 16; ++i) {
                float4 bv = bp[i];
                dot += Cr[i * 4 + 0] * bv.x + Cr[i * 4 + 1] * bv.y
                     + Cr[i * 4 + 2] * bv.z + Cr[i * 4 + 3] * bv.w;
            }
            float w = expf(acs_l - acs_s[si]) * dts[si] * dot;
            const float* xp = &Xt[si][0];
            #pragma unroll
            for (int p = 0; p < 64; ++p) yacc[p] += w * xp[p];
        }
    }

    // gate: u = z*silu(y); write u in place of z (f32); partial sum(u^2)
    float* zrow = zf + (size_t)tl * D_INNER + h * HD;
    float ss = 0.f;
    #pragma unroll
    for (int i = 0; i < 16; ++i) {
        float4 zv = *(const float4*)(zrow + i * 4);
        float u0, u1, u2, u3;
        {
            float y = yacc[i * 4 + 0]; u0 = zv.x * (y / (1.f + expf(-y)));
            y = yacc[i * 4 + 1];       u1 = zv.y * (y / (1.f + expf(-y)));
            y = yacc[i * 4 + 2];       u2 = zv.z * (y / (1.f + expf(-y)));
            y = yacc[i * 4 + 3];       u3 = zv.w * (y / (1.f + expf(-y)));
        }
        ss += u0 * u0 + u1 * u1 + u2 * u2 + u3 * u3;
        *(float4*)(zrow + i * 4) = make_float4(u0, u1, u2, u3);
    }
    usq[(size_t)tl * 64 + h] = ss;
}

// ----- rstd[t] = rsqrt(mean(u^2) + eps) ----------------------------------
__global__ __launch_bounds__(256) void rstd_kernel(const float* __restrict__ usq,
                                                   float* __restrict__ rstd) {
    int t = blockIdx.x * 256 + threadIdx.x;
    float s = 0.f;
    #pragma unroll
    for (int i = 0; i < 16; ++i) {
        float4 v = *(const float4*)(usq + (size_t)t * 64 + i * 4);
        s += v.x + v.y + v.z + v.w;
    }
    rstd[t] = rsqrtf(s / 4096.f + EPS_R);
}

template<bool CF32>
static void run_pipeline(const float* x, const float* w_in, const float* conv_w,
                         const float* conv_b, const float* dt_bias, const float* A_log,
                         const float* D_param, const float* norm_w, const float* w_out,
                         float* out, float* zf, void* cbuf, float* bc, float* dtb,
                         float* acs, float* states, hipStream_t stream) {
    float* usq  = dtb;   // alias: all dt reads complete (sync-bracketed) before usq writes
    float* rstd = acs;   // alias: acs dead after ymerged

    gemm_in<128, 128, 16, CF32><<<dim3(N_ZX / 128, TTOK / 128), 256, 0, stream>>>(
        x, w_in, zf, cbuf);
    dtproj_kernel<<<TTOK / 16, 256, 0, stream>>>(x, w_in, dt_bias, dtb);
    scan_kernel<<<2 * NH, 256, 0, stream>>>(dtb, A_log, acs);
    bcconv_kernel<CF32><<<TTOK, 128, 0, stream>>>(cbuf, conv_w, conv_b, bc);
    chunkstate_kernel<CF32><<<2 * NCH * NH, 256, 0, stream>>>(
        cbuf, bc, conv_w, conv_b, dtb, acs, states);
    chunkscan_kernel<<<2 * NH, 256, 0, stream>>>(acs, states);
    ymerged_kernel<CF32><<<2 * NCH * NH, 256, 0, stream>>>(
        cbuf, bc, conv_w, conv_b, zf, dtb, acs, states, D_param, usq);
    rstd_kernel<<<TTOK / 256, 256, 0, stream>>>(usq, rstd);
    gemm_out<128, 128, 16><<<dim3(D_MODEL / 128, TTOK / 128), 256, 0, stream>>>(
        zf, w_out, out, rstd, norm_w);
}

extern "C" void kernel_launch(void* const* d_in, const int* in_sizes, int n_in,
                              void* d_out, int out_size, void* d_ws, size_t ws_size,
                              hipStream_t stream) {
    const float* x        = (const float*)d_in[0];
    const float* w_in     = (const float*)d_in[1];
    const float* conv_w   = (const float*)d_in[2];
    const float* conv_b   = (const float*)d_in[3];
    const float* dt_bias  = (const float*)d_in[4];
    const float* A_log    = (const float*)d_in[5];
    const float* D_param  = (const float*)d_in[6];
    const float* norm_w   = (const float*)d_in[7];
    const float* w_out    = (const float*)d_in[8];
    float* out = (float*)d_out;

    const size_t sz_zf  = (size_t)TTOK * D_INNER * 4;    // 67,108,864
    const size_t sz_bc  = (size_t)TTOK * 128 * 4;        //  2,097,152
    const size_t sz_dt  = (size_t)TTOK * 64 * 4;         //  1,048,576
    const size_t sz_acs = (size_t)128 * LSEQ * 4;        //  1,048,576
    const size_t sz_st  = (size_t)1024 * 4096 * 4;       // 16,777,216
    const size_t cb_bf  = (size_t)TTOK * XBC_DIM * 2;    // 34,603,008
    const size_t cb_f   = (size_t)TTOK * XBC_DIM * 4;    // 69,206,016
    const size_t fixed  = sz_zf + sz_bc + sz_dt + sz_acs + sz_st;
    const size_t need_bf = fixed + cb_bf;   // 122,683,392 B (~117 MiB)
    const size_t need_f  = fixed + cb_f;    // 157,286,400 B (150 MiB)
    if (ws_size < need_bf) return;          // diagnostic: zero-out -> absmax=max|ref|

    bool cf32 = (ws_size >= need_f);
    char* p = (char*)d_ws;
    float* zf     = (float*)p; p += sz_zf;
    void*  cbuf   = (void*)p;  p += cf32 ? cb_f : cb_bf;
    float* bc     = (float*)p; p += sz_bc;
    float* dtb    = (float*)p; p += sz_dt;
    float* acs    = (float*)p; p += sz_acs;
    float* states = (float*)p; p += sz_st;

    if (cf32)
        run_pipeline<true>(x, w_in, conv_w, conv_b, dt_bias, A_log, D_param,
                           norm_w, w_out, out, zf, cbuf, bc, dtb, acs, states, stream);
    else
        run_pipeline<false>(x, w_in, conv_w, conv_b, dt_bias, A_log, D_param,
                            norm_w, w_out, out, zf, cbuf, bc, dtb, acs, states, stream);
}

// Round 9
// 1407.429 us; speedup vs baseline: 2.5212x; 2.5212x over previous
//
#include <hip/hip_runtime.h>
#include <math.h>

#define D_MODEL   2048
#define D_INNER   4096
#define XBC_DIM   4224
#define D_IN_PROJ 8384
#define NH    64
#define HD    64
#define DS    64
#define LCH   256
#define NCH   8
#define LSEQ  2048
#define TTOK  4096
#define EPS_R 1.1920929e-07f

typedef unsigned short u16;
typedef unsigned int   u32;
typedef _Float16 f16x8 __attribute__((ext_vector_type(8)));
typedef _Float16 f16x4 __attribute__((ext_vector_type(4)));
typedef float    f4v   __attribute__((ext_vector_type(4)));

__device__ __forceinline__ float4 f16_ld4(const _Float16* c, size_t idx) {
    f16x4 v = *(const f16x4*)(c + idx);
    return make_float4((float)v[0], (float)v[1], (float)v[2], (float)v[3]);
}

// ===== f16 MFMA GEMM: C[M][Nloc] = A[M][K] @ W[Nloc][K]^T ================
// f16 inputs (2^-12 rel rounding), f32 accumulate.
// SCALE: A pre-scaled by rs[row]*nw[k] in f32. CF16: f16 C stores, else f32.
template<bool CF16, bool SCALE>
__global__ __launch_bounds__(256) void gemm_mfma(const float* __restrict__ A, int lda,
                                                 const float* __restrict__ W, int ldw,
                                                 void* __restrict__ C, int ldc, int K,
                                                 const float* __restrict__ rs,
                                                 const float* __restrict__ nw) {
    __shared__ __align__(16) _Float16 lds[2][128][40];   // A-tile, W-tile (pad 40)
    const int tid = threadIdx.x;
    const int row0 = blockIdx.y * 128, col0 = blockIdx.x * 128;
    const int lane = tid & 63, wv = tid >> 6;
    const int wr = wv >> 1, wc = wv & 1;            // 2x2 waves of 64x64 out
    const int fr = lane & 15, fk = (lane >> 4) * 8; // fragment row / k-slice

    f4v acc[4][4];
    #pragma unroll
    for (int mi = 0; mi < 4; ++mi)
        #pragma unroll
        for (int ni = 0; ni < 4; ++ni) acc[mi][ni] = (f4v){0.f, 0.f, 0.f, 0.f};

    for (int k0 = 0; k0 < K; k0 += 32) {
        #pragma unroll
        for (int i = 0; i < 4; ++i) {
            int idx = tid + i * 256;
            int r = idx >> 3, kq = (idx & 7) * 4;
            float4 va = *(const float4*)(A + (size_t)(row0 + r) * lda + k0 + kq);
            if constexpr (SCALE) {
                float s = rs[row0 + r];
                float4 w4 = *(const float4*)(nw + k0 + kq);
                va.x *= s * w4.x; va.y *= s * w4.y; va.z *= s * w4.z; va.w *= s * w4.w;
            }
            f16x4 ha = {(_Float16)va.x, (_Float16)va.y, (_Float16)va.z, (_Float16)va.w};
            *(f16x4*)&lds[0][r][kq] = ha;
            float4 vw = *(const float4*)(W + (size_t)(col0 + r) * ldw + k0 + kq);
            f16x4 hw = {(_Float16)vw.x, (_Float16)vw.y, (_Float16)vw.z, (_Float16)vw.w};
            *(f16x4*)&lds[1][r][kq] = hw;
        }
        __syncthreads();

        f16x8 ah[4];
        #pragma unroll
        for (int mi = 0; mi < 4; ++mi)
            ah[mi] = *(const f16x8*)&lds[0][wr * 64 + mi * 16 + fr][fk];
        #pragma unroll
        for (int ni = 0; ni < 4; ++ni) {
            f16x8 bh = *(const f16x8*)&lds[1][wc * 64 + ni * 16 + fr][fk];
            #pragma unroll
            for (int mi = 0; mi < 4; ++mi)
                acc[mi][ni] = __builtin_amdgcn_mfma_f32_16x16x32_f16(ah[mi], bh, acc[mi][ni], 0, 0, 0);
        }
        __syncthreads();
    }

    const int orow = (lane >> 4) * 4;   // C/D: col=lane&15, row=(lane>>4)*4+reg
    #pragma unroll
    for (int mi = 0; mi < 4; ++mi)
        #pragma unroll
        for (int ni = 0; ni < 4; ++ni) {
            int r = row0 + wr * 64 + mi * 16 + orow;
            int c = col0 + wc * 64 + ni * 16 + fr;
            #pragma unroll
            for (int j = 0; j < 4; ++j) {
                if constexpr (CF16)
                    ((_Float16*)C)[(size_t)(r + j) * ldc + c] = (_Float16)acc[mi][ni][j];
                else
                    ((float*)C)[(size_t)(r + j) * ldc + c] = acc[mi][ni][j];
            }
        }
}

// ----- dt projection in pure f32 -----------------------------------------
__global__ __launch_bounds__(256) void dtproj_kernel(const float* __restrict__ x,
                                                     const float* __restrict__ w_in,
                                                     const float* __restrict__ dt_bias,
                                                     float* __restrict__ dt_buf) {
    __shared__ float Xs[16][64];
    __shared__ float Ws[64][65];
    int tid = threadIdx.x;
    int t0 = blockIdx.x * 16;
    int h = tid & 63, trow = tid >> 6;
    float acc[4] = {0.f, 0.f, 0.f, 0.f};
    const float* wdt = w_in + (size_t)(D_INNER + XBC_DIM) * D_MODEL;

    for (int k0 = 0; k0 < D_MODEL; k0 += 64) {
        __syncthreads();
        {
            int r = tid >> 4, c4 = (tid & 15) * 4;
            *(float4*)&Xs[r][c4] = *(const float4*)(x + (size_t)(t0 + r) * D_MODEL + k0 + c4);
        }
        #pragma unroll
        for (int i = 0; i < 4; ++i) {
            int ff = tid + i * 256;
            int r = ff >> 4, c4 = (ff & 15) * 4;
            float4 v = *(const float4*)(wdt + (size_t)r * D_MODEL + k0 + c4);
            Ws[r][c4 + 0] = v.x; Ws[r][c4 + 1] = v.y;
            Ws[r][c4 + 2] = v.z; Ws[r][c4 + 3] = v.w;
        }
        __syncthreads();
        #pragma unroll 16
        for (int k = 0; k < 64; ++k) {
            float wv = Ws[h][k];
            #pragma unroll
            for (int i = 0; i < 4; ++i)
                acc[i] += Xs[trow + i * 4][k] * wv;
        }
    }
    float bias = dt_bias[h];
    #pragma unroll
    for (int i = 0; i < 4; ++i) {
        float xv = acc[i] + bias;
        float sp = (xv > 20.f) ? xv : log1pf(expf(xv));
        dt_buf[(size_t)(t0 + trow + i * 4) * 64 + h] = sp;
    }
}

// ------------- per-(b,h) chunk-local inclusive cumsum of a=A*dt ----------
__global__ __launch_bounds__(256) void scan_kernel(const float* __restrict__ dt_buf,
                                                   const float* __restrict__ A_log,
                                                   float* __restrict__ acs) {
    int b = blockIdx.x >> 6, h = blockIdx.x & 63;
    float Ah = -expf(A_log[h]);
    __shared__ float s[256];
    int tid = threadIdx.x;
    for (int c = 0; c < NCH; ++c) {
        int t = b * LSEQ + c * LCH + tid;
        float a = Ah * dt_buf[t * 64 + h];
        s[tid] = a;
        __syncthreads();
        for (int off = 1; off < 256; off <<= 1) {
            float v = (tid >= off) ? s[tid - off] : 0.f;
            __syncthreads();
            s[tid] += v;
            __syncthreads();
        }
        acs[(size_t)blockIdx.x * LSEQ + c * LCH + tid] = s[tid];
        __syncthreads();
    }
}

// ---- convolved B/C (128 channels) in f32 --------------------------------
__global__ __launch_bounds__(128) void bcconv_kernel(const _Float16* __restrict__ cbuf,
                                                     const float* __restrict__ cw,
                                                     const float* __restrict__ cb,
                                                     float* __restrict__ bc) {
    int chl = threadIdx.x;
    int t = blockIdx.x;
    int b = t >> 11, lp = t & 2047;
    int ch = D_INNER + chl;
    float acc = cb[ch];
    #pragma unroll
    for (int j = 0; j < 4; ++j) {
        int lj = lp - 3 + j;
        if (lj >= 0)
            acc += cw[ch * 4 + j] * (float)cbuf[(size_t)(b * LSEQ + lj) * XBC_DIM + ch];
    }
    bc[(size_t)t * 128 + chl] = acc / (1.f + expf(-acc));
}

// conv-fused staging of one 64x64 X tile (unscaled silu(conv)) ------------
__device__ __forceinline__ void stage_x_tile(const _Float16* cbuf, const float* cw,
                                             const float* cb, int b, int lp0,
                                             int h, int tid, float Xt[64][64]) {
    #pragma unroll
    for (int i = 0; i < 4; ++i) {
        int ff = tid + i * 256;
        int r = ff >> 4, c4 = ff & 15;
        int lp = lp0 + r;
        int ch0 = h * HD + c4 * 4;
        float tp[4][4];
        #pragma unroll
        for (int k = 0; k < 4; ++k)
            *(float4*)tp[k] = *(const float4*)(cw + (size_t)(ch0 + k) * 4);
        float a0 = cb[ch0], a1 = cb[ch0 + 1], a2 = cb[ch0 + 2], a3 = cb[ch0 + 3];
        #pragma unroll
        for (int j = 0; j < 4; ++j) {
            int lj = lp - 3 + j;
            if (lj >= 0) {
                float4 v = f16_ld4(cbuf, (size_t)(b * LSEQ + lj) * XBC_DIM + ch0);
                a0 += tp[0][j] * v.x; a1 += tp[1][j] * v.y;
                a2 += tp[2][j] * v.z; a3 += tp[3][j] * v.w;
            }
        }
        Xt[r][c4 * 4 + 0] = a0 / (1.f + expf(-a0));
        Xt[r][c4 * 4 + 1] = a1 / (1.f + expf(-a1));
        Xt[r][c4 * 4 + 2] = a2 / (1.f + expf(-a2));
        Xt[r][c4 * 4 + 3] = a3 / (1.f + expf(-a3));
    }
}

// ----- chunk states: states[p][n] = sum_s B[s,n]·dec[s]·dt[s]·X[s,p] -----
__global__ __launch_bounds__(256) void chunkstate_kernel(const _Float16* __restrict__ cbuf,
                                                         const float* __restrict__ bc,
                                                         const float* __restrict__ cw,
                                                         const float* __restrict__ cb,
                                                         const float* __restrict__ dt_buf,
                                                         const float* __restrict__ acs,
                                                         float* __restrict__ states) {
    int h = blockIdx.x & 63;
    int c = (blockIdx.x >> 6) & 7;
    int b = blockIdx.x >> 9;
    int tbase = b * LSEQ + c * LCH;
    const float* acs_blk = acs + (size_t)(b * 64 + h) * LSEQ + c * LCH;
    float acs_last = acs_blk[LCH - 1];

    __shared__ float Bt[64][64];
    __shared__ float Xt[64][64];
    __shared__ float dec[64];

    float4 acc4[4];
    #pragma unroll
    for (int i = 0; i < 4; ++i) acc4[i] = make_float4(0.f, 0.f, 0.f, 0.f);
    int tid = threadIdx.x;
    int p = tid & 63, n0 = (tid >> 6) * 16;

    for (int s0 = 0; s0 < LCH; s0 += 64) {
        __syncthreads();
        #pragma unroll
        for (int i = 0; i < 4; ++i) {
            int ff = tid + i * 256;
            int r = ff >> 4, c4 = ff & 15;
            *(float4*)&Bt[r][c4 * 4] =
                *(const float4*)(bc + (size_t)(tbase + s0 + r) * 128 + c4 * 4);
        }
        stage_x_tile(cbuf, cw, cb, b, c * LCH + s0, h, tid, Xt);
        if (tid < 64)
            dec[tid] = expf(acs_last - acs_blk[s0 + tid])
                     * dt_buf[(size_t)(tbase + s0 + tid) * 64 + h];
        __syncthreads();

        for (int si = 0; si < 64; ++si) {
            float xv = Xt[si][p] * dec[si];
            const float4* bp = (const float4*)&Bt[si][n0];
            #pragma unroll
            for (int i = 0; i < 4; ++i) {
                float4 bv = bp[i];
                acc4[i].x += xv * bv.x; acc4[i].y += xv * bv.y;
                acc4[i].z += xv * bv.z; acc4[i].w += xv * bv.w;
            }
        }
    }
    float4* sp = (float4*)(states + (size_t)blockIdx.x * 4096 + p * 64 + n0);
    #pragma unroll
    for (int i = 0; i < 4; ++i) sp[i] = acc4[i];
}

// ----- inter-chunk recurrence per (b,h); in-place ------------------------
__global__ __launch_bounds__(256) void chunkscan_kernel(const float* __restrict__ acs,
                                                        float* __restrict__ states) {
    int b = blockIdx.x >> 6, h = blockIdx.x & 63;
    int tid = threadIdx.x;
    float4 S4[4];
    #pragma unroll
    for (int i = 0; i < 4; ++i) S4[i] = make_float4(0.f, 0.f, 0.f, 0.f);
    const float* acs_blk = acs + (size_t)blockIdx.x * LSEQ;
    for (int c = 0; c < NCH; ++c) {
        float d = expf(acs_blk[c * LCH + LCH - 1]);
        float4* sp = (float4*)(states + ((size_t)(b * NCH + c) * NH + h) * 4096 + tid * 16);
        float4 t4[4];
        #pragma unroll
        for (int i = 0; i < 4; ++i) t4[i] = sp[i];
        #pragma unroll
        for (int i = 0; i < 4; ++i) sp[i] = S4[i];
        #pragma unroll
        for (int i = 0; i < 4; ++i) {
            S4[i].x = d * S4[i].x + t4[i].x;
            S4[i].y = d * S4[i].y + t4[i].y;
            S4[i].z = d * S4[i].z + t4[i].z;
            S4[i].w = d * S4[i].w + t4[i].w;
        }
    }
}

// ----- merged Y + gate: u = z*silu(Y_off+Y_diag+xs*D), u in-place over z -
__global__ __launch_bounds__(256) void ymerged_kernel(const _Float16* __restrict__ cbuf,
                                                      const float* __restrict__ bc,
                                                      const float* __restrict__ cw,
                                                      const float* __restrict__ cb,
                                                      float* __restrict__ zf,
                                                      const float* __restrict__ dt_buf,
                                                      const float* __restrict__ acs,
                                                      const float* __restrict__ states,
                                                      const float* __restrict__ D_param,
                                                      float* __restrict__ usq) {
    int h = blockIdx.x & 63;
    int c = (blockIdx.x >> 6) & 7;
    int b = blockIdx.x >> 9;
    int l = threadIdx.x;
    int tid = l;
    int tbase = b * LSEQ + c * LCH;
    int tl = tbase + l;
    const float* acs_blk = acs + (size_t)(b * 64 + h) * LSEQ + c * LCH;
    float acs_l = acs_blk[l];
    float Dp = D_param[h];

    __shared__ float Slds[4096];
    __shared__ float Bt[64][64];
    __shared__ float Xt[64][64];
    __shared__ float acs_s[64];
    __shared__ float dts[64];

    const float4* sp = (const float4*)(states + (size_t)blockIdx.x * 4096);
    for (int i = tid; i < 1024; i += 256) ((float4*)Slds)[i] = sp[i];

    float Cr[64];
    #pragma unroll
    for (int i = 0; i < 16; ++i) {
        float4 v = *(const float4*)(bc + (size_t)tl * 128 + 64 + i * 4);
        Cr[i * 4 + 0] = v.x; Cr[i * 4 + 1] = v.y;
        Cr[i * 4 + 2] = v.z; Cr[i * 4 + 3] = v.w;
    }
    __syncthreads();

    float e = expf(acs_l);
    float yacc[64];
    #pragma unroll 4
    for (int p = 0; p < HD; ++p) {
        float dot = 0.f;
        const float4* srow = (const float4*)&Slds[p * 64];
        #pragma unroll
        for (int i = 0; i < 16; ++i) {
            float4 sv = srow[i];
            dot += Cr[i * 4 + 0] * sv.x + Cr[i * 4 + 1] * sv.y
                 + Cr[i * 4 + 2] * sv.z + Cr[i * 4 + 3] * sv.w;
        }
        yacc[p] = e * dot;
    }

    for (int s0 = 0; s0 < LCH; s0 += 64) {
        __syncthreads();
        #pragma unroll
        for (int i = 0; i < 4; ++i) {
            int ff = tid + i * 256;
            int r = ff >> 4, c4 = ff & 15;
            *(float4*)&Bt[r][c4 * 4] =
                *(const float4*)(bc + (size_t)(tbase + s0 + r) * 128 + c4 * 4);
        }
        stage_x_tile(cbuf, cw, cb, b, c * LCH + s0, h, tid, Xt);
        if (tid < 64) {
            acs_s[tid] = acs_blk[s0 + tid];
            dts[tid] = dt_buf[(size_t)(tbase + s0 + tid) * 64 + h];
        }
        __syncthreads();

        if (l >= s0 && l < s0 + 64) {
            const float* xr = &Xt[l - s0][0];
            #pragma unroll
            for (int p = 0; p < 64; ++p) yacc[p] += xr[p] * Dp;
        }

        int smax = l - s0;
        int slim = (smax >= 63) ? 64 : (smax + 1);
        for (int si = 0; si < slim; ++si) {
            float dot = 0.f;
            const float4* bp = (const float4*)&Bt[si][0];
            #pragma unroll
            for (int i = 0; i < 16; ++i) {
                float4 bv = bp[i];
                dot += Cr[i * 4 + 0] * bv.x + Cr[i * 4 + 1] * bv.y
                     + Cr[i * 4 + 2] * bv.z + Cr[i * 4 + 3] * bv.w;
            }
            float w = expf(acs_l - acs_s[si]) * dts[si] * dot;
            const float* xp = &Xt[si][0];
            #pragma unroll
            for (int p = 0; p < 64; ++p) yacc[p] += w * xp[p];
        }
    }

    float* zrow = zf + (size_t)tl * D_INNER + h * HD;
    float ss = 0.f;
    #pragma unroll
    for (int i = 0; i < 16; ++i) {
        float4 zv = *(const float4*)(zrow + i * 4);
        float u0, u1, u2, u3;
        {
            float y = yacc[i * 4 + 0]; u0 = zv.x * (y / (1.f + expf(-y)));
            y = yacc[i * 4 + 1];       u1 = zv.y * (y / (1.f + expf(-y)));
            y = yacc[i * 4 + 2];       u2 = zv.z * (y / (1.f + expf(-y)));
            y = yacc[i * 4 + 3];       u3 = zv.w * (y / (1.f + expf(-y)));
        }
        ss += u0 * u0 + u1 * u1 + u2 * u2 + u3 * u3;
        *(float4*)(zrow + i * 4) = make_float4(u0, u1, u2, u3);
    }
    usq[(size_t)tl * 64 + h] = ss;
}

// ----- rstd[t] = rsqrt(mean(u^2) + eps) ----------------------------------
__global__ __launch_bounds__(256) void rstd_kernel(const float* __restrict__ usq,
                                                   float* __restrict__ rstd) {
    int t = blockIdx.x * 256 + threadIdx.x;
    float s = 0.f;
    #pragma unroll
    for (int i = 0; i < 16; ++i) {
        float4 v = *(const float4*)(usq + (size_t)t * 64 + i * 4);
        s += v.x + v.y + v.z + v.w;
    }
    rstd[t] = rsqrtf(s / 4096.f + EPS_R);
}

extern "C" void kernel_launch(void* const* d_in, const int* in_sizes, int n_in,
                              void* d_out, int out_size, void* d_ws, size_t ws_size,
                              hipStream_t stream) {
    const float* x        = (const float*)d_in[0];
    const float* w_in     = (const float*)d_in[1];
    const float* conv_w   = (const float*)d_in[2];
    const float* conv_b   = (const float*)d_in[3];
    const float* dt_bias  = (const float*)d_in[4];
    const float* A_log    = (const float*)d_in[5];
    const float* D_param  = (const float*)d_in[6];
    const float* norm_w   = (const float*)d_in[7];
    const float* w_out    = (const float*)d_in[8];
    float* out = (float*)d_out;

    const size_t sz_zf  = (size_t)TTOK * D_INNER * 4;    // 67,108,864
    const size_t sz_cb  = (size_t)TTOK * XBC_DIM * 2;    // 34,603,008 (f16)
    const size_t sz_bc  = (size_t)TTOK * 128 * 4;        //  2,097,152
    const size_t sz_dt  = (size_t)TTOK * 64 * 4;         //  1,048,576
    const size_t sz_acs = (size_t)128 * LSEQ * 4;        //  1,048,576
    const size_t sz_st  = (size_t)1024 * 4096 * 4;       // 16,777,216
    const size_t need   = sz_zf + sz_cb + sz_bc + sz_dt + sz_acs + sz_st; // 122,683,392
    if (ws_size < need) return;

    char* p = (char*)d_ws;
    float*    zf     = (float*)p;    p += sz_zf;
    _Float16* cbuf   = (_Float16*)p; p += sz_cb;
    float*    bc     = (float*)p;    p += sz_bc;
    float*    dtb    = (float*)p;    p += sz_dt;
    float*    acs    = (float*)p;    p += sz_acs;
    float*    states = (float*)p;    p += sz_st;
    float* usq  = dtb;   // alias: dt reads all complete before usq writes
    float* rstd = acs;   // alias: acs dead after ymerged

    // 1a. z = x @ w_in[0:4096]^T   (f16 MFMA, f32 out)
    gemm_mfma<false, false><<<dim3(32, 32), 256, 0, stream>>>(
        x, D_MODEL, w_in, D_MODEL, zf, D_INNER, D_MODEL, nullptr, nullptr);
    // 1b. conv-in = x @ w_in[4096:8320]^T  (f16 MFMA, f16 out)
    gemm_mfma<true, false><<<dim3(33, 32), 256, 0, stream>>>(
        x, D_MODEL, w_in + (size_t)D_INNER * D_MODEL, D_MODEL,
        cbuf, XBC_DIM, D_MODEL, nullptr, nullptr);
    // 2. dt (pure f32)
    dtproj_kernel<<<TTOK / 16, 256, 0, stream>>>(x, w_in, dt_bias, dtb);
    // 3. per-chunk cumsum of A*dt
    scan_kernel<<<2 * NH, 256, 0, stream>>>(dtb, A_log, acs);
    // 4. convolved B/C
    bcconv_kernel<<<TTOK, 128, 0, stream>>>(cbuf, conv_w, conv_b, bc);
    // 5. chunk states
    chunkstate_kernel<<<2 * NCH * NH, 256, 0, stream>>>(
        cbuf, bc, conv_w, conv_b, dtb, acs, states);
    // 6. inter-chunk recurrence
    chunkscan_kernel<<<2 * NH, 256, 0, stream>>>(acs, states);
    // 7. merged Y + gate (u in-place over z)
    ymerged_kernel<<<2 * NCH * NH, 256, 0, stream>>>(
        cbuf, bc, conv_w, conv_b, zf, dtb, acs, states, D_param, usq);
    // 8. rstd
    rstd_kernel<<<TTOK / 256, 256, 0, stream>>>(usq, rstd);
    // 9. out = (u*rstd*nw) @ w_out^T  (f16 MFMA with fused scale, f32 out)
    gemm_mfma<false, true><<<dim3(16, 32), 256, 0, stream>>>(
        zf, D_INNER, w_out, D_INNER, out, D_MODEL, D_INNER, rstd, norm_w);
}

// Round 10
// 913.145 us; speedup vs baseline: 3.8860x; 1.5413x over previous
//
#include <hip/hip_runtime.h>
#include <math.h>

#define D_MODEL   2048
#define D_INNER   4096
#define XBC_DIM   4224
#define D_IN_PROJ 8384
#define NH    64
#define HD    64
#define DS    64
#define LCH   256
#define NCH   8
#define LSEQ  2048
#define TTOK  4096
#define EPS_R 1.1920929e-07f

#define XT_S 264   // XT inner stride (f16 elems)
#define WL_S 72    // W scratch inner stride (f16 elems)

typedef unsigned short u16;
typedef unsigned int   u32;
typedef _Float16 f16x8 __attribute__((ext_vector_type(8)));
typedef _Float16 f16x4 __attribute__((ext_vector_type(4)));
typedef float    f4v   __attribute__((ext_vector_type(4)));

__device__ __forceinline__ float4 f16_ld4(const _Float16* c, size_t idx) {
    f16x4 v = *(const f16x4*)(c + idx);
    return make_float4((float)v[0], (float)v[1], (float)v[2], (float)v[3]);
}
__device__ __forceinline__ f16x8 cvt8(float4 a, float4 b) {
    f16x8 r;
    r[0] = (_Float16)a.x; r[1] = (_Float16)a.y; r[2] = (_Float16)a.z; r[3] = (_Float16)a.w;
    r[4] = (_Float16)b.x; r[5] = (_Float16)b.y; r[6] = (_Float16)b.z; r[7] = (_Float16)b.w;
    return r;
}

// ===== f16 MFMA GEMM: C[M][Nloc] = A[M][K] @ W[Nloc][K]^T ================
template<bool CF16, bool SCALE>
__global__ __launch_bounds__(256) void gemm_mfma(const float* __restrict__ A, int lda,
                                                 const float* __restrict__ W, int ldw,
                                                 void* __restrict__ C, int ldc, int K,
                                                 const float* __restrict__ rs,
                                                 const float* __restrict__ nw) {
    __shared__ __align__(16) _Float16 lds[2][128][40];
    const int tid = threadIdx.x;
    const int row0 = blockIdx.y * 128, col0 = blockIdx.x * 128;
    const int lane = tid & 63, wv = tid >> 6;
    const int wr = wv >> 1, wc = wv & 1;
    const int fr = lane & 15, fk = (lane >> 4) * 8;

    f4v acc[4][4];
    #pragma unroll
    for (int mi = 0; mi < 4; ++mi)
        #pragma unroll
        for (int ni = 0; ni < 4; ++ni) acc[mi][ni] = (f4v){0.f, 0.f, 0.f, 0.f};

    for (int k0 = 0; k0 < K; k0 += 32) {
        #pragma unroll
        for (int i = 0; i < 4; ++i) {
            int idx = tid + i * 256;
            int r = idx >> 3, kq = (idx & 7) * 4;
            float4 va = *(const float4*)(A + (size_t)(row0 + r) * lda + k0 + kq);
            if constexpr (SCALE) {
                float s = rs[row0 + r];
                float4 w4 = *(const float4*)(nw + k0 + kq);
                va.x *= s * w4.x; va.y *= s * w4.y; va.z *= s * w4.z; va.w *= s * w4.w;
            }
            f16x4 ha = {(_Float16)va.x, (_Float16)va.y, (_Float16)va.z, (_Float16)va.w};
            *(f16x4*)&lds[0][r][kq] = ha;
            float4 vw = *(const float4*)(W + (size_t)(col0 + r) * ldw + k0 + kq);
            f16x4 hw = {(_Float16)vw.x, (_Float16)vw.y, (_Float16)vw.z, (_Float16)vw.w};
            *(f16x4*)&lds[1][r][kq] = hw;
        }
        __syncthreads();

        f16x8 ah[4];
        #pragma unroll
        for (int mi = 0; mi < 4; ++mi)
            ah[mi] = *(const f16x8*)&lds[0][wr * 64 + mi * 16 + fr][fk];
        #pragma unroll
        for (int ni = 0; ni < 4; ++ni) {
            f16x8 bh = *(const f16x8*)&lds[1][wc * 64 + ni * 16 + fr][fk];
            #pragma unroll
            for (int mi = 0; mi < 4; ++mi)
                acc[mi][ni] = __builtin_amdgcn_mfma_f32_16x16x32_f16(ah[mi], bh, acc[mi][ni], 0, 0, 0);
        }
        __syncthreads();
    }

    const int orow = (lane >> 4) * 4;
    #pragma unroll
    for (int mi = 0; mi < 4; ++mi)
        #pragma unroll
        for (int ni = 0; ni < 4; ++ni) {
            int r = row0 + wr * 64 + mi * 16 + orow;
            int c = col0 + wc * 64 + ni * 16 + fr;
            #pragma unroll
            for (int j = 0; j < 4; ++j) {
                if constexpr (CF16)
                    ((_Float16*)C)[(size_t)(r + j) * ldc + c] = (_Float16)acc[mi][ni][j];
                else
                    ((float*)C)[(size_t)(r + j) * ldc + c] = acc[mi][ni][j];
            }
        }
}

// ----- dt projection in pure f32 -----------------------------------------
__global__ __launch_bounds__(256) void dtproj_kernel(const float* __restrict__ x,
                                                     const float* __restrict__ w_in,
                                                     const float* __restrict__ dt_bias,
                                                     float* __restrict__ dt_buf) {
    __shared__ float Xs[16][64];
    __shared__ float Ws[64][65];
    int tid = threadIdx.x;
    int t0 = blockIdx.x * 16;
    int h = tid & 63, trow = tid >> 6;
    float acc[4] = {0.f, 0.f, 0.f, 0.f};
    const float* wdt = w_in + (size_t)(D_INNER + XBC_DIM) * D_MODEL;

    for (int k0 = 0; k0 < D_MODEL; k0 += 64) {
        __syncthreads();
        {
            int r = tid >> 4, c4 = (tid & 15) * 4;
            *(float4*)&Xs[r][c4] = *(const float4*)(x + (size_t)(t0 + r) * D_MODEL + k0 + c4);
        }
        #pragma unroll
        for (int i = 0; i < 4; ++i) {
            int ff = tid + i * 256;
            int r = ff >> 4, c4 = (ff & 15) * 4;
            float4 v = *(const float4*)(wdt + (size_t)r * D_MODEL + k0 + c4);
            Ws[r][c4 + 0] = v.x; Ws[r][c4 + 1] = v.y;
            Ws[r][c4 + 2] = v.z; Ws[r][c4 + 3] = v.w;
        }
        __syncthreads();
        #pragma unroll 16
        for (int k = 0; k < 64; ++k) {
            float wv = Ws[h][k];
            #pragma unroll
            for (int i = 0; i < 4; ++i)
                acc[i] += Xs[trow + i * 4][k] * wv;
        }
    }
    float bias = dt_bias[h];
    #pragma unroll
    for (int i = 0; i < 4; ++i) {
        float xv = acc[i] + bias;
        float sp = (xv > 20.f) ? xv : log1pf(expf(xv));
        dt_buf[(size_t)(t0 + trow + i * 4) * 64 + h] = sp;
    }
}

// ------------- per-(b,h) chunk-local inclusive cumsum of a=A*dt ----------
__global__ __launch_bounds__(256) void scan_kernel(const float* __restrict__ dt_buf,
                                                   const float* __restrict__ A_log,
                                                   float* __restrict__ acs) {
    int b = blockIdx.x >> 6, h = blockIdx.x & 63;
    float Ah = -expf(A_log[h]);
    __shared__ float s[256];
    int tid = threadIdx.x;
    for (int c = 0; c < NCH; ++c) {
        int t = b * LSEQ + c * LCH + tid;
        float a = Ah * dt_buf[t * 64 + h];
        s[tid] = a;
        __syncthreads();
        for (int off = 1; off < 256; off <<= 1) {
            float v = (tid >= off) ? s[tid - off] : 0.f;
            __syncthreads();
            s[tid] += v;
            __syncthreads();
        }
        acs[(size_t)blockIdx.x * LSEQ + c * LCH + tid] = s[tid];
        __syncthreads();
    }
}

// ---- convolved B/C (128 channels) in f32 --------------------------------
__global__ __launch_bounds__(128) void bcconv_kernel(const _Float16* __restrict__ cbuf,
                                                     const float* __restrict__ cw,
                                                     const float* __restrict__ cb,
                                                     float* __restrict__ bc) {
    int chl = threadIdx.x;
    int t = blockIdx.x;
    int b = t >> 11, lp = t & 2047;
    int ch = D_INNER + chl;
    float acc = cb[ch];
    #pragma unroll
    for (int j = 0; j < 4; ++j) {
        int lj = lp - 3 + j;
        if (lj >= 0)
            acc += cw[ch * 4 + j] * (float)cbuf[(size_t)(b * LSEQ + lj) * XBC_DIM + ch];
    }
    bc[(size_t)t * 128 + chl] = acc / (1.f + expf(-acc));
}

// conv-fused staging of one 64x64 X tile (row-major, for chunkstate) ------
__device__ __forceinline__ void stage_x_tile(const _Float16* cbuf, const float* cw,
                                             const float* cb, int b, int lp0,
                                             int h, int tid, float Xt[64][64]) {
    #pragma unroll
    for (int i = 0; i < 4; ++i) {
        int ff = tid + i * 256;
        int r = ff >> 4, c4 = ff & 15;
        int lp = lp0 + r;
        int ch0 = h * HD + c4 * 4;
        float tp[4][4];
        #pragma unroll
        for (int k = 0; k < 4; ++k)
            *(float4*)tp[k] = *(const float4*)(cw + (size_t)(ch0 + k) * 4);
        float a0 = cb[ch0], a1 = cb[ch0 + 1], a2 = cb[ch0 + 2], a3 = cb[ch0 + 3];
        #pragma unroll
        for (int j = 0; j < 4; ++j) {
            int lj = lp - 3 + j;
            if (lj >= 0) {
                float4 v = f16_ld4(cbuf, (size_t)(b * LSEQ + lj) * XBC_DIM + ch0);
                a0 += tp[0][j] * v.x; a1 += tp[1][j] * v.y;
                a2 += tp[2][j] * v.z; a3 += tp[3][j] * v.w;
            }
        }
        Xt[r][c4 * 4 + 0] = a0 / (1.f + expf(-a0));
        Xt[r][c4 * 4 + 1] = a1 / (1.f + expf(-a1));
        Xt[r][c4 * 4 + 2] = a2 / (1.f + expf(-a2));
        Xt[r][c4 * 4 + 3] = a3 / (1.f + expf(-a3));
    }
}

// ----- chunk states: states[p][n] = sum_s B[s,n]·dec[s]·dt[s]·X[s,p] -----
__global__ __launch_bounds__(256) void chunkstate_kernel(const _Float16* __restrict__ cbuf,
                                                         const float* __restrict__ bc,
                                                         const float* __restrict__ cw,
                                                         const float* __restrict__ cb,
                                                         const float* __restrict__ dt_buf,
                                                         const float* __restrict__ acs,
                                                         float* __restrict__ states) {
    int h = blockIdx.x & 63;
    int c = (blockIdx.x >> 6) & 7;
    int b = blockIdx.x >> 9;
    int tbase = b * LSEQ + c * LCH;
    const float* acs_blk = acs + (size_t)(b * 64 + h) * LSEQ + c * LCH;
    float acs_last = acs_blk[LCH - 1];

    __shared__ float Bt[64][64];
    __shared__ float Xt[64][64];
    __shared__ float dec[64];

    float4 acc4[4];
    #pragma unroll
    for (int i = 0; i < 4; ++i) acc4[i] = make_float4(0.f, 0.f, 0.f, 0.f);
    int tid = threadIdx.x;
    int p = tid & 63, n0 = (tid >> 6) * 16;

    for (int s0 = 0; s0 < LCH; s0 += 64) {
        __syncthreads();
        #pragma unroll
        for (int i = 0; i < 4; ++i) {
            int ff = tid + i * 256;
            int r = ff >> 4, c4 = ff & 15;
            *(float4*)&Bt[r][c4 * 4] =
                *(const float4*)(bc + (size_t)(tbase + s0 + r) * 128 + c4 * 4);
        }
        stage_x_tile(cbuf, cw, cb, b, c * LCH + s0, h, tid, Xt);
        if (tid < 64)
            dec[tid] = expf(acs_last - acs_blk[s0 + tid])
                     * dt_buf[(size_t)(tbase + s0 + tid) * 64 + h];
        __syncthreads();

        for (int si = 0; si < 64; ++si) {
            float xv = Xt[si][p] * dec[si];
            const float4* bp = (const float4*)&Bt[si][n0];
            #pragma unroll
            for (int i = 0; i < 4; ++i) {
                float4 bv = bp[i];
                acc4[i].x += xv * bv.x; acc4[i].y += xv * bv.y;
                acc4[i].z += xv * bv.z; acc4[i].w += xv * bv.w;
            }
        }
    }
    float4* sp = (float4*)(states + (size_t)blockIdx.x * 4096 + p * 64 + n0);
    #pragma unroll
    for (int i = 0; i < 4; ++i) sp[i] = acc4[i];
}

// ----- inter-chunk recurrence per (b,h); in-place ------------------------
__global__ __launch_bounds__(256) void chunkscan_kernel(const float* __restrict__ acs,
                                                        float* __restrict__ states) {
    int b = blockIdx.x >> 6, h = blockIdx.x & 63;
    int tid = threadIdx.x;
    float4 S4[4];
    #pragma unroll
    for (int i = 0; i < 4; ++i) S4[i] = make_float4(0.f, 0.f, 0.f, 0.f);
    const float* acs_blk = acs + (size_t)blockIdx.x * LSEQ;
    for (int c = 0; c < NCH; ++c) {
        float d = expf(acs_blk[c * LCH + LCH - 1]);
        float4* sp = (float4*)(states + ((size_t)(b * NCH + c) * NH + h) * 4096 + tid * 16);
        float4 t4[4];
        #pragma unroll
        for (int i = 0; i < 4; ++i) t4[i] = sp[i];
        #pragma unroll
        for (int i = 0; i < 4; ++i) sp[i] = S4[i];
        #pragma unroll
        for (int i = 0; i < 4; ++i) {
            S4[i].x = d * S4[i].x + t4[i].x;
            S4[i].y = d * S4[i].y + t4[i].y;
            S4[i].z = d * S4[i].z + t4[i].z;
            S4[i].w = d * S4[i].w + t4[i].w;
        }
    }
}

// ===== MFMA ymerged: Y = Yoff + Ydiag + X·D; u = z·silu(Y) in-place ======
// Per (b,c,h): flash-attention-shaped. 4 waves; wave w owns l-rows [w·64,w·64+64).
// S = C·B^T via MFMA (frags straight from bc, f32->f16); W = mask·exp·dt ⊙ S
// goes through per-wave LDS scratch to re-lay as A-fragments; PV via MFMA with
// X^T staged in LDS (ds_read_b128). Yoff = (e_l·C)·Sin^T via MFMA.
__global__ __launch_bounds__(256) void ymerged_mfma(const _Float16* __restrict__ cbuf,
                                                    const float* __restrict__ bc,
                                                    const float* __restrict__ cw,
                                                    const float* __restrict__ cb,
                                                    float* __restrict__ zf,
                                                    const float* __restrict__ dt_buf,
                                                    const float* __restrict__ acs,
                                                    const float* __restrict__ states,
                                                    const float* __restrict__ D_param,
                                                    float* __restrict__ usq) {
    const int h = blockIdx.x & 63;
    const int c = (blockIdx.x >> 6) & 7;
    const int b = blockIdx.x >> 9;
    const int tbase = b * LSEQ + c * LCH;
    const int tid = threadIdx.x, lane = tid & 63, w = tid >> 6;
    const int fr = lane & 15, fq = lane >> 4;

    __shared__ __align__(16) _Float16 XT[64][XT_S];      // X^T [p][s]
    __shared__ __align__(16) _Float16 Wl[4][64][WL_S];   // per-wave W scratch
    __shared__ float acs_s[256];
    __shared__ float dts[256];

    const float* acs_blk = acs + (size_t)(b * 64 + h) * LSEQ + c * LCH;
    acs_s[tid] = acs_blk[tid];
    dts[tid] = dt_buf[(size_t)(tbase + tid) * 64 + h];

    // ---- stage X^T (conv + silu, f32 math, f16 store) ----
    #pragma unroll 4
    for (int i = 0; i < 16; ++i) {
        int u = tid + i * 256;
        int s = u >> 4, pq = (u & 15) * 4;
        int lp = c * LCH + s;                 // position within sequence
        int ch0 = h * HD + pq;
        float tp[4][4];
        #pragma unroll
        for (int k = 0; k < 4; ++k)
            *(float4*)tp[k] = *(const float4*)(cw + (size_t)(ch0 + k) * 4);
        float a0 = cb[ch0], a1 = cb[ch0 + 1], a2 = cb[ch0 + 2], a3 = cb[ch0 + 3];
        #pragma unroll
        for (int j = 0; j < 4; ++j) {
            int lj = lp - 3 + j;
            if (lj >= 0) {
                float4 v = f16_ld4(cbuf, (size_t)(b * LSEQ + lj) * XBC_DIM + ch0);
                a0 += tp[0][j] * v.x; a1 += tp[1][j] * v.y;
                a2 += tp[2][j] * v.z; a3 += tp[3][j] * v.w;
            }
        }
        XT[pq + 0][s] = (_Float16)(a0 / (1.f + expf(-a0)));
        XT[pq + 1][s] = (_Float16)(a1 / (1.f + expf(-a1)));
        XT[pq + 2][s] = (_Float16)(a2 / (1.f + expf(-a2)));
        XT[pq + 3][s] = (_Float16)(a3 / (1.f + expf(-a3)));
    }
    __syncthreads();

    // ---- C fragments (A-operand, reused everywhere) ----
    f16x8 cf[4][2];
    #pragma unroll
    for (int ls = 0; ls < 4; ++ls)
        #pragma unroll
        for (int kf = 0; kf < 2; ++kf) {
            const float* src = bc + (size_t)(tbase + w * 64 + ls * 16 + fr) * 128
                             + 64 + kf * 32 + fq * 8;
            cf[ls][kf] = cvt8(*(const float4*)src, *(const float4*)(src + 4));
        }

    // acs_l per (lsub, reg)
    float acsl[16];
    #pragma unroll
    for (int ls = 0; ls < 4; ++ls)
        #pragma unroll
        for (int r = 0; r < 4; ++r)
            acsl[ls * 4 + r] = acs_s[w * 64 + ls * 16 + fq * 4 + r];

    f4v Y[4][4];
    // ---- Y_off = e_l · C @ Sin^T ----
    {
        f16x8 sf[4][2];
        #pragma unroll
        for (int ps = 0; ps < 4; ++ps)
            #pragma unroll
            for (int kf = 0; kf < 2; ++kf) {
                const float* src = states + (size_t)blockIdx.x * 4096
                                 + (ps * 16 + fr) * 64 + kf * 32 + fq * 8;
                sf[ps][kf] = cvt8(*(const float4*)src, *(const float4*)(src + 4));
            }
        f4v yo[4][4];
        #pragma unroll
        for (int ls = 0; ls < 4; ++ls)
            #pragma unroll
            for (int ps = 0; ps < 4; ++ps) {
                yo[ls][ps] = (f4v){0.f, 0.f, 0.f, 0.f};
                yo[ls][ps] = __builtin_amdgcn_mfma_f32_16x16x32_f16(cf[ls][0], sf[ps][0], yo[ls][ps], 0, 0, 0);
                yo[ls][ps] = __builtin_amdgcn_mfma_f32_16x16x32_f16(cf[ls][1], sf[ps][1], yo[ls][ps], 0, 0, 0);
            }
        #pragma unroll
        for (int ls = 0; ls < 4; ++ls)
            #pragma unroll
            for (int ps = 0; ps < 4; ++ps)
                #pragma unroll
                for (int r = 0; r < 4; ++r)
                    Y[ls][ps][r] = expf(acsl[ls * 4 + r]) * yo[ls][ps][r];
    }

    // ---- Y_diag: s-tiles 0..w ----
    for (int st = 0; st <= w; ++st) {
        // B fragments (B-operand of S = C·B^T)
        f16x8 bf[4][2];
        #pragma unroll
        for (int ss = 0; ss < 4; ++ss)
            #pragma unroll
            for (int kf = 0; kf < 2; ++kf) {
                const float* src = bc + (size_t)(tbase + st * 64 + ss * 16 + fr) * 128
                                 + kf * 32 + fq * 8;
                bf[ss][kf] = cvt8(*(const float4*)src, *(const float4*)(src + 4));
            }
        f4v S[4][4];
        #pragma unroll
        for (int ls = 0; ls < 4; ++ls)
            #pragma unroll
            for (int ss = 0; ss < 4; ++ss) {
                S[ls][ss] = (f4v){0.f, 0.f, 0.f, 0.f};
                S[ls][ss] = __builtin_amdgcn_mfma_f32_16x16x32_f16(cf[ls][0], bf[ss][0], S[ls][ss], 0, 0, 0);
                S[ls][ss] = __builtin_amdgcn_mfma_f32_16x16x32_f16(cf[ls][1], bf[ss][1], S[ls][ss], 0, 0, 0);
            }
        // weight + mask, write W scratch (C/D layout -> [l][s])
        #pragma unroll
        for (int ss = 0; ss < 4; ++ss) {
            int s_idx = st * 64 + ss * 16 + fr;
            float as = acs_s[s_idx];
            float dv = dts[s_idx];
            #pragma unroll
            for (int ls = 0; ls < 4; ++ls)
                #pragma unroll
                for (int r = 0; r < 4; ++r) {
                    int l_idx = w * 64 + ls * 16 + fq * 4 + r;
                    float wv = (s_idx <= l_idx)
                             ? expf(acsl[ls * 4 + r] - as) * dv * S[ls][ss][r] : 0.f;
                    Wl[w][ls * 16 + fq * 4 + r][ss * 16 + fr] = (_Float16)wv;
                }
        }
        // W A-frags (contiguous) + X B-frags (from XT), PV
        f16x8 wf[4][2], xf[4][2];
        #pragma unroll
        for (int ls = 0; ls < 4; ++ls)
            #pragma unroll
            for (int kf = 0; kf < 2; ++kf)
                wf[ls][kf] = *(const f16x8*)&Wl[w][ls * 16 + fr][kf * 32 + fq * 8];
        #pragma unroll
        for (int ps = 0; ps < 4; ++ps)
            #pragma unroll
            for (int kf = 0; kf < 2; ++kf)
                xf[ps][kf] = *(const f16x8*)&XT[ps * 16 + fr][st * 64 + kf * 32 + fq * 8];
        #pragma unroll
        for (int ls = 0; ls < 4; ++ls)
            #pragma unroll
            for (int ps = 0; ps < 4; ++ps) {
                Y[ls][ps] = __builtin_amdgcn_mfma_f32_16x16x32_f16(wf[ls][0], xf[ps][0], Y[ls][ps], 0, 0, 0);
                Y[ls][ps] = __builtin_amdgcn_mfma_f32_16x16x32_f16(wf[ls][1], xf[ps][1], Y[ls][ps], 0, 0, 0);
            }
    }

    // ---- D-term + gate + usq ----
    float Dp = D_param[h];
    #pragma unroll
    for (int ls = 0; ls < 4; ++ls)
        #pragma unroll
        for (int r = 0; r < 4; ++r) {
            int l = w * 64 + ls * 16 + fq * 4 + r;
            int tl = tbase + l;
            float ss_acc = 0.f;
            #pragma unroll
            for (int ps = 0; ps < 4; ++ps) {
                int p = ps * 16 + fr;
                float y = Y[ls][ps][r] + (float)XT[p][l] * Dp;
                float* zp = zf + (size_t)tl * D_INNER + h * HD + p;
                float uv = (*zp) * (y / (1.f + expf(-y)));
                *zp = uv;
                ss_acc += uv * uv;
            }
            ss_acc += __shfl_xor(ss_acc, 1);
            ss_acc += __shfl_xor(ss_acc, 2);
            ss_acc += __shfl_xor(ss_acc, 4);
            ss_acc += __shfl_xor(ss_acc, 8);
            if (fr == 0) usq[(size_t)tl * 64 + h] = ss_acc;
        }
}

// ----- rstd[t] = rsqrt(mean(u^2) + eps) ----------------------------------
__global__ __launch_bounds__(256) void rstd_kernel(const float* __restrict__ usq,
                                                   float* __restrict__ rstd) {
    int t = blockIdx.x * 256 + threadIdx.x;
    float s = 0.f;
    #pragma unroll
    for (int i = 0; i < 16; ++i) {
        float4 v = *(const float4*)(usq + (size_t)t * 64 + i * 4);
        s += v.x + v.y + v.z + v.w;
    }
    rstd[t] = rsqrtf(s / 4096.f + EPS_R);
}

extern "C" void kernel_launch(void* const* d_in, const int* in_sizes, int n_in,
                              void* d_out, int out_size, void* d_ws, size_t ws_size,
                              hipStream_t stream) {
    const float* x        = (const float*)d_in[0];
    const float* w_in     = (const float*)d_in[1];
    const float* conv_w   = (const float*)d_in[2];
    const float* conv_b   = (const float*)d_in[3];
    const float* dt_bias  = (const float*)d_in[4];
    const float* A_log    = (const float*)d_in[5];
    const float* D_param  = (const float*)d_in[6];
    const float* norm_w   = (const float*)d_in[7];
    const float* w_out    = (const float*)d_in[8];
    float* out = (float*)d_out;

    const size_t sz_zf  = (size_t)TTOK * D_INNER * 4;    // 67,108,864
    const size_t sz_cb  = (size_t)TTOK * XBC_DIM * 2;    // 34,603,008 (f16)
    const size_t sz_bc  = (size_t)TTOK * 128 * 4;        //  2,097,152
    const size_t sz_dt  = (size_t)TTOK * 64 * 4;         //  1,048,576
    const size_t sz_acs = (size_t)128 * LSEQ * 4;        //  1,048,576
    const size_t sz_st  = (size_t)1024 * 4096 * 4;       // 16,777,216
    const size_t need   = sz_zf + sz_cb + sz_bc + sz_dt + sz_acs + sz_st;
    if (ws_size < need) return;

    char* p = (char*)d_ws;
    float*    zf     = (float*)p;    p += sz_zf;
    _Float16* cbuf   = (_Float16*)p; p += sz_cb;
    float*    bc     = (float*)p;    p += sz_bc;
    float*    dtb    = (float*)p;    p += sz_dt;
    float*    acs    = (float*)p;    p += sz_acs;
    float*    states = (float*)p;    p += sz_st;
    float* usq  = dtb;   // alias: dt reads all complete before usq writes
    float* rstd = acs;   // alias: acs dead after ymerged

    gemm_mfma<false, false><<<dim3(32, 32), 256, 0, stream>>>(
        x, D_MODEL, w_in, D_MODEL, zf, D_INNER, D_MODEL, nullptr, nullptr);
    gemm_mfma<true, false><<<dim3(33, 32), 256, 0, stream>>>(
        x, D_MODEL, w_in + (size_t)D_INNER * D_MODEL, D_MODEL,
        cbuf, XBC_DIM, D_MODEL, nullptr, nullptr);
    dtproj_kernel<<<TTOK / 16, 256, 0, stream>>>(x, w_in, dt_bias, dtb);
    scan_kernel<<<2 * NH, 256, 0, stream>>>(dtb, A_log, acs);
    bcconv_kernel<<<TTOK, 128, 0, stream>>>(cbuf, conv_w, conv_b, bc);
    chunkstate_kernel<<<2 * NCH * NH, 256, 0, stream>>>(
        cbuf, bc, conv_w, conv_b, dtb, acs, states);
    chunkscan_kernel<<<2 * NH, 256, 0, stream>>>(acs, states);
    ymerged_mfma<<<2 * NCH * NH, 256, 0, stream>>>(
        cbuf, bc, conv_w, conv_b, zf, dtb, acs, states, D_param, usq);
    rstd_kernel<<<TTOK / 256, 256, 0, stream>>>(usq, rstd);
    gemm_mfma<false, true><<<dim3(16, 32), 256, 0, stream>>>(
        zf, D_INNER, w_out, D_INNER, out, D_MODEL, D_INNER, rstd, norm_w);
}

// Round 11
// 695.724 us; speedup vs baseline: 5.1004x; 1.3125x over previous
//
#include <hip/hip_runtime.h>
#include <math.h>

#define D_MODEL   2048
#define D_INNER   4096
#define XBC_DIM   4224
#define D_IN_PROJ 8384
#define N_ZX      8320
#define NH    64
#define HD    64
#define DS    64
#define LCH   256
#define NCH   8
#define LSEQ  2048
#define TTOK  4096
#define EPS_R 1.1920929e-07f

#define XT_S 264   // XT inner stride (f16 elems)
#define WL_S 72    // W scratch inner stride (f16 elems)

typedef unsigned short u16;
typedef unsigned int   u32;
typedef _Float16 f16x8 __attribute__((ext_vector_type(8)));
typedef _Float16 f16x4 __attribute__((ext_vector_type(4)));
typedef float    f4v   __attribute__((ext_vector_type(4)));

__device__ __forceinline__ float4 f16_ld4(const _Float16* c, size_t idx) {
    f16x4 v = *(const f16x4*)(c + idx);
    return make_float4((float)v[0], (float)v[1], (float)v[2], (float)v[3]);
}
__device__ __forceinline__ f16x8 cvt8(float4 a, float4 b) {
    f16x8 r;
    r[0] = (_Float16)a.x; r[1] = (_Float16)a.y; r[2] = (_Float16)a.z; r[3] = (_Float16)a.w;
    r[4] = (_Float16)b.x; r[5] = (_Float16)b.y; r[6] = (_Float16)b.z; r[7] = (_Float16)b.w;
    return r;
}
__device__ __forceinline__ float fexp(float x)  { return __expf(x); }
__device__ __forceinline__ float fsilu(float x) { return x / (1.f + __expf(-x)); }

// ---- one-time f32 -> f16 conversions ------------------------------------
__global__ __launch_bounds__(256) void cvt16_kernel(const float* __restrict__ src,
                                                    _Float16* __restrict__ dst,
                                                    size_t n8) {
    size_t i = (size_t)blockIdx.x * 256 + threadIdx.x;
    if (i >= n8) return;
    float4 a = *(const float4*)(src + i * 8);
    float4 b = *(const float4*)(src + i * 8 + 4);
    *(f16x8*)(dst + i * 8) = cvt8(a, b);
}
// wout16[c][k] = w_out[c][k] * nw[k]
__global__ __launch_bounds__(256) void cvt_wout_kernel(const float* __restrict__ w,
                                                       const float* __restrict__ nw,
                                                       _Float16* __restrict__ dst) {
    size_t i = (size_t)blockIdx.x * 256 + threadIdx.x;
    size_t base = i * 8;
    int k = (int)(base & 4095);
    float4 a = *(const float4*)(w + base);
    float4 b = *(const float4*)(w + base + 4);
    float4 na = *(const float4*)(nw + k);
    float4 nb = *(const float4*)(nw + k + 4);
    a.x *= na.x; a.y *= na.y; a.z *= na.z; a.w *= na.w;
    b.x *= nb.x; b.y *= nb.y; b.z *= nb.z; b.w *= nb.w;
    *(f16x8*)(dst + base) = cvt8(a, b);
}

// ===== pure-f16 MFMA GEMM, BK=64, 128x128 tile ===========================
// in_proj: C cols <4096 -> zf (f16, ldc 4096); >=4096 -> cbuf (f16, ldc 4224)
__global__ __launch_bounds__(256) void gemm_in16(const _Float16* __restrict__ A,
                                                 const _Float16* __restrict__ W,
                                                 _Float16* __restrict__ zf,
                                                 _Float16* __restrict__ cbuf) {
    __shared__ __align__(16) _Float16 lsA[128][72];
    __shared__ __align__(16) _Float16 lsB[128][72];
    const int tid = threadIdx.x;
    const int row0 = blockIdx.y * 128, col0 = blockIdx.x * 128;
    const int lane = tid & 63, wv = tid >> 6;
    const int wr = wv >> 1, wc = wv & 1;
    const int fr = lane & 15, fq = lane >> 4;

    f4v acc[4][4];
    #pragma unroll
    for (int mi = 0; mi < 4; ++mi)
        #pragma unroll
        for (int ni = 0; ni < 4; ++ni) acc[mi][ni] = (f4v){0.f, 0.f, 0.f, 0.f};

    for (int k0 = 0; k0 < D_MODEL; k0 += 64) {
        #pragma unroll
        for (int i = 0; i < 4; ++i) {
            int idx = tid + i * 256;
            int r = idx >> 3, kc = (idx & 7) * 8;
            *(f16x8*)&lsA[r][kc] = *(const f16x8*)(A + (size_t)(row0 + r) * D_MODEL + k0 + kc);
            *(f16x8*)&lsB[r][kc] = *(const f16x8*)(W + (size_t)(col0 + r) * D_MODEL + k0 + kc);
        }
        __syncthreads();
        f16x8 ah[4][2];
        #pragma unroll
        for (int mi = 0; mi < 4; ++mi)
            #pragma unroll
            for (int kf = 0; kf < 2; ++kf)
                ah[mi][kf] = *(const f16x8*)&lsA[wr * 64 + mi * 16 + fr][kf * 32 + fq * 8];
        #pragma unroll
        for (int ni = 0; ni < 4; ++ni) {
            #pragma unroll
            for (int kf = 0; kf < 2; ++kf) {
                f16x8 bh = *(const f16x8*)&lsB[wc * 64 + ni * 16 + fr][kf * 32 + fq * 8];
                #pragma unroll
                for (int mi = 0; mi < 4; ++mi)
                    acc[mi][ni] = __builtin_amdgcn_mfma_f32_16x16x32_f16(ah[mi][kf], bh, acc[mi][ni], 0, 0, 0);
            }
        }
        __syncthreads();
    }

    const int orow = fq * 4;
    #pragma unroll
    for (int mi = 0; mi < 4; ++mi)
        #pragma unroll
        for (int ni = 0; ni < 4; ++ni) {
            int r = row0 + wr * 64 + mi * 16 + orow;
            int cc = col0 + wc * 64 + ni * 16 + fr;
            if (col0 < D_INNER) {
                #pragma unroll
                for (int j = 0; j < 4; ++j)
                    zf[(size_t)(r + j) * D_INNER + cc] = (_Float16)acc[mi][ni][j];
            } else {
                #pragma unroll
                for (int j = 0; j < 4; ++j)
                    cbuf[(size_t)(r + j) * XBC_DIM + (cc - D_INNER)] = (_Float16)acc[mi][ni][j];
            }
        }
}

// out_proj: out[r][c] = rstd[r] * sum_k u[r,k]*wout16[c,k]  (f32 out)
__global__ __launch_bounds__(256) void gemm_out16(const _Float16* __restrict__ A,
                                                  const _Float16* __restrict__ W,
                                                  float* __restrict__ C,
                                                  const float* __restrict__ rstd) {
    __shared__ __align__(16) _Float16 lsA[128][72];
    __shared__ __align__(16) _Float16 lsB[128][72];
    const int tid = threadIdx.x;
    const int row0 = blockIdx.y * 128, col0 = blockIdx.x * 128;
    const int lane = tid & 63, wv = tid >> 6;
    const int wr = wv >> 1, wc = wv & 1;
    const int fr = lane & 15, fq = lane >> 4;

    f4v acc[4][4];
    #pragma unroll
    for (int mi = 0; mi < 4; ++mi)
        #pragma unroll
        for (int ni = 0; ni < 4; ++ni) acc[mi][ni] = (f4v){0.f, 0.f, 0.f, 0.f};

    for (int k0 = 0; k0 < D_INNER; k0 += 64) {
        #pragma unroll
        for (int i = 0; i < 4; ++i) {
            int idx = tid + i * 256;
            int r = idx >> 3, kc = (idx & 7) * 8;
            *(f16x8*)&lsA[r][kc] = *(const f16x8*)(A + (size_t)(row0 + r) * D_INNER + k0 + kc);
            *(f16x8*)&lsB[r][kc] = *(const f16x8*)(W + (size_t)(col0 + r) * D_INNER + k0 + kc);
        }
        __syncthreads();
        f16x8 ah[4][2];
        #pragma unroll
        for (int mi = 0; mi < 4; ++mi)
            #pragma unroll
            for (int kf = 0; kf < 2; ++kf)
                ah[mi][kf] = *(const f16x8*)&lsA[wr * 64 + mi * 16 + fr][kf * 32 + fq * 8];
        #pragma unroll
        for (int ni = 0; ni < 4; ++ni) {
            #pragma unroll
            for (int kf = 0; kf < 2; ++kf) {
                f16x8 bh = *(const f16x8*)&lsB[wc * 64 + ni * 16 + fr][kf * 32 + fq * 8];
                #pragma unroll
                for (int mi = 0; mi < 4; ++mi)
                    acc[mi][ni] = __builtin_amdgcn_mfma_f32_16x16x32_f16(ah[mi][kf], bh, acc[mi][ni], 0, 0, 0);
            }
        }
        __syncthreads();
    }

    const int orow = fq * 4;
    #pragma unroll
    for (int mi = 0; mi < 4; ++mi)
        #pragma unroll
        for (int ni = 0; ni < 4; ++ni) {
            int r = row0 + wr * 64 + mi * 16 + orow;
            int cc = col0 + wc * 64 + ni * 16 + fr;
            #pragma unroll
            for (int j = 0; j < 4; ++j)
                C[(size_t)(r + j) * D_MODEL + cc] = acc[mi][ni][j] * rstd[r + j];
        }
}

// ----- dt projection in pure f32 (precise libm: dt is exp-amplified) -----
__global__ __launch_bounds__(256) void dtproj_kernel(const float* __restrict__ x,
                                                     const float* __restrict__ w_in,
                                                     const float* __restrict__ dt_bias,
                                                     float* __restrict__ dt_buf) {
    __shared__ float Xs[16][64];
    __shared__ float Ws[64][65];
    int tid = threadIdx.x;
    int t0 = blockIdx.x * 16;
    int h = tid & 63, trow = tid >> 6;
    float acc[4] = {0.f, 0.f, 0.f, 0.f};
    const float* wdt = w_in + (size_t)(D_INNER + XBC_DIM) * D_MODEL;

    for (int k0 = 0; k0 < D_MODEL; k0 += 64) {
        __syncthreads();
        {
            int r = tid >> 4, c4 = (tid & 15) * 4;
            *(float4*)&Xs[r][c4] = *(const float4*)(x + (size_t)(t0 + r) * D_MODEL + k0 + c4);
        }
        #pragma unroll
        for (int i = 0; i < 4; ++i) {
            int ff = tid + i * 256;
            int r = ff >> 4, c4 = (ff & 15) * 4;
            float4 v = *(const float4*)(wdt + (size_t)r * D_MODEL + k0 + c4);
            Ws[r][c4 + 0] = v.x; Ws[r][c4 + 1] = v.y;
            Ws[r][c4 + 2] = v.z; Ws[r][c4 + 3] = v.w;
        }
        __syncthreads();
        #pragma unroll 16
        for (int k = 0; k < 64; ++k) {
            float wv = Ws[h][k];
            #pragma unroll
            for (int i = 0; i < 4; ++i)
                acc[i] += Xs[trow + i * 4][k] * wv;
        }
    }
    float bias = dt_bias[h];
    #pragma unroll
    for (int i = 0; i < 4; ++i) {
        float xv = acc[i] + bias;
        float sp = (xv > 20.f) ? xv : log1pf(expf(xv));
        dt_buf[(size_t)(t0 + trow + i * 4) * 64 + h] = sp;
    }
}

// ------------- per-(b,h) chunk-local inclusive cumsum of a=A*dt ----------
__global__ __launch_bounds__(256) void scan_kernel(const float* __restrict__ dt_buf,
                                                   const float* __restrict__ A_log,
                                                   float* __restrict__ acs) {
    int b = blockIdx.x >> 6, h = blockIdx.x & 63;
    float Ah = -expf(A_log[h]);
    __shared__ float s[256];
    int tid = threadIdx.x;
    for (int c = 0; c < NCH; ++c) {
        int t = b * LSEQ + c * LCH + tid;
        float a = Ah * dt_buf[t * 64 + h];
        s[tid] = a;
        __syncthreads();
        for (int off = 1; off < 256; off <<= 1) {
            float v = (tid >= off) ? s[tid - off] : 0.f;
            __syncthreads();
            s[tid] += v;
            __syncthreads();
        }
        acs[(size_t)blockIdx.x * LSEQ + c * LCH + tid] = s[tid];
        __syncthreads();
    }
}

// ---- convolved B/C (128 channels) in f32 --------------------------------
__global__ __launch_bounds__(128) void bcconv_kernel(const _Float16* __restrict__ cbuf,
                                                     const float* __restrict__ cw,
                                                     const float* __restrict__ cb,
                                                     float* __restrict__ bc) {
    int chl = threadIdx.x;
    int t = blockIdx.x;
    int b = t >> 11, lp = t & 2047;
    int ch = D_INNER + chl;
    float acc = cb[ch];
    #pragma unroll
    for (int j = 0; j < 4; ++j) {
        int lj = lp - 3 + j;
        if (lj >= 0)
            acc += cw[ch * 4 + j] * (float)cbuf[(size_t)(b * LSEQ + lj) * XBC_DIM + ch];
    }
    bc[(size_t)t * 128 + chl] = fsilu(acc);
}

// conv-fused staging of one 64x64 X tile (row-major, for chunkstate) ------
__device__ __forceinline__ void stage_x_tile(const _Float16* cbuf, const float* cw,
                                             const float* cb, int b, int lp0,
                                             int h, int tid, float Xt[64][64]) {
    #pragma unroll
    for (int i = 0; i < 4; ++i) {
        int ff = tid + i * 256;
        int r = ff >> 4, c4 = ff & 15;
        int lp = lp0 + r;
        int ch0 = h * HD + c4 * 4;
        float tp[4][4];
        #pragma unroll
        for (int k = 0; k < 4; ++k)
            *(float4*)tp[k] = *(const float4*)(cw + (size_t)(ch0 + k) * 4);
        float a0 = cb[ch0], a1 = cb[ch0 + 1], a2 = cb[ch0 + 2], a3 = cb[ch0 + 3];
        #pragma unroll
        for (int j = 0; j < 4; ++j) {
            int lj = lp - 3 + j;
            if (lj >= 0) {
                float4 v = f16_ld4(cbuf, (size_t)(b * LSEQ + lj) * XBC_DIM + ch0);
                a0 += tp[0][j] * v.x; a1 += tp[1][j] * v.y;
                a2 += tp[2][j] * v.z; a3 += tp[3][j] * v.w;
            }
        }
        Xt[r][c4 * 4 + 0] = fsilu(a0);
        Xt[r][c4 * 4 + 1] = fsilu(a1);
        Xt[r][c4 * 4 + 2] = fsilu(a2);
        Xt[r][c4 * 4 + 3] = fsilu(a3);
    }
}

// ----- chunk states: states[p][n] = sum_s B[s,n]·dec[s]·dt[s]·X[s,p] -----
__global__ __launch_bounds__(256) void chunkstate_kernel(const _Float16* __restrict__ cbuf,
                                                         const float* __restrict__ bc,
                                                         const float* __restrict__ cw,
                                                         const float* __restrict__ cb,
                                                         const float* __restrict__ dt_buf,
                                                         const float* __restrict__ acs,
                                                         float* __restrict__ states) {
    int h = blockIdx.x & 63;
    int c = (blockIdx.x >> 6) & 7;
    int b = blockIdx.x >> 9;
    int tbase = b * LSEQ + c * LCH;
    const float* acs_blk = acs + (size_t)(b * 64 + h) * LSEQ + c * LCH;
    float acs_last = acs_blk[LCH - 1];

    __shared__ float Bt[64][64];
    __shared__ float Xt[64][64];
    __shared__ float dec[64];

    float4 acc4[4];
    #pragma unroll
    for (int i = 0; i < 4; ++i) acc4[i] = make_float4(0.f, 0.f, 0.f, 0.f);
    int tid = threadIdx.x;
    int p = tid & 63, n0 = (tid >> 6) * 16;

    for (int s0 = 0; s0 < LCH; s0 += 64) {
        __syncthreads();
        #pragma unroll
        for (int i = 0; i < 4; ++i) {
            int ff = tid + i * 256;
            int r = ff >> 4, c4 = ff & 15;
            *(float4*)&Bt[r][c4 * 4] =
                *(const float4*)(bc + (size_t)(tbase + s0 + r) * 128 + c4 * 4);
        }
        stage_x_tile(cbuf, cw, cb, b, c * LCH + s0, h, tid, Xt);
        if (tid < 64)
            dec[tid] = fexp(acs_last - acs_blk[s0 + tid])
                     * dt_buf[(size_t)(tbase + s0 + tid) * 64 + h];
        __syncthreads();

        for (int si = 0; si < 64; ++si) {
            float xv = Xt[si][p] * dec[si];
            const float4* bp = (const float4*)&Bt[si][n0];
            #pragma unroll
            for (int i = 0; i < 4; ++i) {
                float4 bv = bp[i];
                acc4[i].x += xv * bv.x; acc4[i].y += xv * bv.y;
                acc4[i].z += xv * bv.z; acc4[i].w += xv * bv.w;
            }
        }
    }
    float4* sp = (float4*)(states + (size_t)blockIdx.x * 4096 + p * 64 + n0);
    #pragma unroll
    for (int i = 0; i < 4; ++i) sp[i] = acc4[i];
}

// ----- inter-chunk recurrence per (b,h); in-place ------------------------
__global__ __launch_bounds__(256) void chunkscan_kernel(const float* __restrict__ acs,
                                                        float* __restrict__ states) {
    int b = blockIdx.x >> 6, h = blockIdx.x & 63;
    int tid = threadIdx.x;
    float4 S4[4];
    #pragma unroll
    for (int i = 0; i < 4; ++i) S4[i] = make_float4(0.f, 0.f, 0.f, 0.f);
    const float* acs_blk = acs + (size_t)blockIdx.x * LSEQ;
    for (int c = 0; c < NCH; ++c) {
        float d = expf(acs_blk[c * LCH + LCH - 1]);
        float4* sp = (float4*)(states + ((size_t)(b * NCH + c) * NH + h) * 4096 + tid * 16);
        float4 t4[4];
        #pragma unroll
        for (int i = 0; i < 4; ++i) t4[i] = sp[i];
        #pragma unroll
        for (int i = 0; i < 4; ++i) sp[i] = S4[i];
        #pragma unroll
        for (int i = 0; i < 4; ++i) {
            S4[i].x = d * S4[i].x + t4[i].x;
            S4[i].y = d * S4[i].y + t4[i].y;
            S4[i].z = d * S4[i].z + t4[i].z;
            S4[i].w = d * S4[i].w + t4[i].w;
        }
    }
}

// ===== MFMA ymerged: Y = Yoff + Ydiag + X·D; u = z·silu(Y), z/u f16 ======
__global__ __launch_bounds__(256) void ymerged_mfma(const _Float16* __restrict__ cbuf,
                                                    const float* __restrict__ bc,
                                                    const float* __restrict__ cw,
                                                    const float* __restrict__ cb,
                                                    _Float16* __restrict__ zf,
                                                    const float* __restrict__ dt_buf,
                                                    const float* __restrict__ acs,
                                                    const float* __restrict__ states,
                                                    const float* __restrict__ D_param,
                                                    float* __restrict__ usq) {
    const int h = blockIdx.x & 63;
    const int c = (blockIdx.x >> 6) & 7;
    const int b = blockIdx.x >> 9;
    const int tbase = b * LSEQ + c * LCH;
    const int tid = threadIdx.x, lane = tid & 63, w = tid >> 6;
    const int fr = lane & 15, fq = lane >> 4;

    __shared__ __align__(16) _Float16 XT[64][XT_S];      // X^T [p][s]
    __shared__ __align__(16) _Float16 Wl[4][64][WL_S];   // per-wave W scratch
    __shared__ float acs_s[256];
    __shared__ float dts[256];

    const float* acs_blk = acs + (size_t)(b * 64 + h) * LSEQ + c * LCH;
    acs_s[tid] = acs_blk[tid];
    dts[tid] = dt_buf[(size_t)(tbase + tid) * 64 + h];

    // ---- stage X^T (conv + silu, f32 math, f16 store) ----
    #pragma unroll 4
    for (int i = 0; i < 16; ++i) {
        int u = tid + i * 256;
        int s = u >> 4, pq = (u & 15) * 4;
        int lp = c * LCH + s;
        int ch0 = h * HD + pq;
        float tp[4][4];
        #pragma unroll
        for (int k = 0; k < 4; ++k)
            *(float4*)tp[k] = *(const float4*)(cw + (size_t)(ch0 + k) * 4);
        float a0 = cb[ch0], a1 = cb[ch0 + 1], a2 = cb[ch0 + 2], a3 = cb[ch0 + 3];
        #pragma unroll
        for (int j = 0; j < 4; ++j) {
            int lj = lp - 3 + j;
            if (lj >= 0) {
                float4 v = f16_ld4(cbuf, (size_t)(b * LSEQ + lj) * XBC_DIM + ch0);
                a0 += tp[0][j] * v.x; a1 += tp[1][j] * v.y;
                a2 += tp[2][j] * v.z; a3 += tp[3][j] * v.w;
            }
        }
        XT[pq + 0][s] = (_Float16)fsilu(a0);
        XT[pq + 1][s] = (_Float16)fsilu(a1);
        XT[pq + 2][s] = (_Float16)fsilu(a2);
        XT[pq + 3][s] = (_Float16)fsilu(a3);
    }
    __syncthreads();

    // ---- C fragments (A-operand, reused everywhere) ----
    f16x8 cf[4][2];
    #pragma unroll
    for (int ls = 0; ls < 4; ++ls)
        #pragma unroll
        for (int kf = 0; kf < 2; ++kf) {
            const float* src = bc + (size_t)(tbase + w * 64 + ls * 16 + fr) * 128
                             + 64 + kf * 32 + fq * 8;
            cf[ls][kf] = cvt8(*(const float4*)src, *(const float4*)(src + 4));
        }

    float acsl[16];
    #pragma unroll
    for (int ls = 0; ls < 4; ++ls)
        #pragma unroll
        for (int r = 0; r < 4; ++r)
            acsl[ls * 4 + r] = acs_s[w * 64 + ls * 16 + fq * 4 + r];

    f4v Y[4][4];
    // ---- Y_off = e_l · C @ Sin^T ----
    {
        f16x8 sf[4][2];
        #pragma unroll
        for (int ps = 0; ps < 4; ++ps)
            #pragma unroll
            for (int kf = 0; kf < 2; ++kf) {
                const float* src = states + (size_t)blockIdx.x * 4096
                                 + (ps * 16 + fr) * 64 + kf * 32 + fq * 8;
                sf[ps][kf] = cvt8(*(const float4*)src, *(const float4*)(src + 4));
            }
        f4v yo[4][4];
        #pragma unroll
        for (int ls = 0; ls < 4; ++ls)
            #pragma unroll
            for (int ps = 0; ps < 4; ++ps) {
                yo[ls][ps] = (f4v){0.f, 0.f, 0.f, 0.f};
                yo[ls][ps] = __builtin_amdgcn_mfma_f32_16x16x32_f16(cf[ls][0], sf[ps][0], yo[ls][ps], 0, 0, 0);
                yo[ls][ps] = __builtin_amdgcn_mfma_f32_16x16x32_f16(cf[ls][1], sf[ps][1], yo[ls][ps], 0, 0, 0);
            }
        #pragma unroll
        for (int ls = 0; ls < 4; ++ls)
            #pragma unroll
            for (int ps = 0; ps < 4; ++ps)
                #pragma unroll
                for (int r = 0; r < 4; ++r)
                    Y[ls][ps][r] = fexp(acsl[ls * 4 + r]) * yo[ls][ps][r];
    }

    // ---- Y_diag: s-tiles 0..w ----
    for (int st = 0; st <= w; ++st) {
        f16x8 bf[4][2];
        #pragma unroll
        for (int ss = 0; ss < 4; ++ss)
            #pragma unroll
            for (int kf = 0; kf < 2; ++kf) {
                const float* src = bc + (size_t)(tbase + st * 64 + ss * 16 + fr) * 128
                                 + kf * 32 + fq * 8;
                bf[ss][kf] = cvt8(*(const float4*)src, *(const float4*)(src + 4));
            }
        f4v S[4][4];
        #pragma unroll
        for (int ls = 0; ls < 4; ++ls)
            #pragma unroll
            for (int ss = 0; ss < 4; ++ss) {
                S[ls][ss] = (f4v){0.f, 0.f, 0.f, 0.f};
                S[ls][ss] = __builtin_amdgcn_mfma_f32_16x16x32_f16(cf[ls][0], bf[ss][0], S[ls][ss], 0, 0, 0);
                S[ls][ss] = __builtin_amdgcn_mfma_f32_16x16x32_f16(cf[ls][1], bf[ss][1], S[ls][ss], 0, 0, 0);
            }
        #pragma unroll
        for (int ss = 0; ss < 4; ++ss) {
            int s_idx = st * 64 + ss * 16 + fr;
            float as = acs_s[s_idx];
            float dv = dts[s_idx];
            #pragma unroll
            for (int ls = 0; ls < 4; ++ls)
                #pragma unroll
                for (int r = 0; r < 4; ++r) {
                    int l_idx = w * 64 + ls * 16 + fq * 4 + r;
                    float wv = (s_idx <= l_idx)
                             ? fexp(acsl[ls * 4 + r] - as) * dv * S[ls][ss][r] : 0.f;
                    Wl[w][ls * 16 + fq * 4 + r][ss * 16 + fr] = (_Float16)wv;
                }
        }
        f16x8 wf[4][2], xf[4][2];
        #pragma unroll
        for (int ls = 0; ls < 4; ++ls)
            #pragma unroll
            for (int kf = 0; kf < 2; ++kf)
                wf[ls][kf] = *(const f16x8*)&Wl[w][ls * 16 + fr][kf * 32 + fq * 8];
        #pragma unroll
        for (int ps = 0; ps < 4; ++ps)
            #pragma unroll
            for (int kf = 0; kf < 2; ++kf)
                xf[ps][kf] = *(const f16x8*)&XT[ps * 16 + fr][st * 64 + kf * 32 + fq * 8];
        #pragma unroll
        for (int ls = 0; ls < 4; ++ls)
            #pragma unroll
            for (int ps = 0; ps < 4; ++ps) {
                Y[ls][ps] = __builtin_amdgcn_mfma_f32_16x16x32_f16(wf[ls][0], xf[ps][0], Y[ls][ps], 0, 0, 0);
                Y[ls][ps] = __builtin_amdgcn_mfma_f32_16x16x32_f16(wf[ls][1], xf[ps][1], Y[ls][ps], 0, 0, 0);
            }
    }

    // ---- D-term + gate + usq (z/u f16) ----
    float Dp = D_param[h];
    #pragma unroll
    for (int ls = 0; ls < 4; ++ls)
        #pragma unroll
        for (int r = 0; r < 4; ++r) {
            int l = w * 64 + ls * 16 + fq * 4 + r;
            int tl = tbase + l;
            float ss_acc = 0.f;
            #pragma unroll
            for (int ps = 0; ps < 4; ++ps) {
                int p = ps * 16 + fr;
                float y = Y[ls][ps][r] + (float)XT[p][l] * Dp;
                _Float16* zp = zf + (size_t)tl * D_INNER + h * HD + p;
                float uv = (float)(*zp) * fsilu(y);
                *zp = (_Float16)uv;
                ss_acc += uv * uv;
            }
            ss_acc += __shfl_xor(ss_acc, 1);
            ss_acc += __shfl_xor(ss_acc, 2);
            ss_acc += __shfl_xor(ss_acc, 4);
            ss_acc += __shfl_xor(ss_acc, 8);
            if (fr == 0) usq[(size_t)tl * 64 + h] = ss_acc;
        }
}

// ----- rstd[t] = rsqrt(mean(u^2) + eps) ----------------------------------
__global__ __launch_bounds__(256) void rstd_kernel(const float* __restrict__ usq,
                                                   float* __restrict__ rstd) {
    int t = blockIdx.x * 256 + threadIdx.x;
    float s = 0.f;
    #pragma unroll
    for (int i = 0; i < 16; ++i) {
        float4 v = *(const float4*)(usq + (size_t)t * 64 + i * 4);
        s += v.x + v.y + v.z + v.w;
    }
    rstd[t] = rsqrtf(s / 4096.f + EPS_R);
}

extern "C" void kernel_launch(void* const* d_in, const int* in_sizes, int n_in,
                              void* d_out, int out_size, void* d_ws, size_t ws_size,
                              hipStream_t stream) {
    const float* x        = (const float*)d_in[0];
    const float* w_in     = (const float*)d_in[1];
    const float* conv_w   = (const float*)d_in[2];
    const float* conv_b   = (const float*)d_in[3];
    const float* dt_bias  = (const float*)d_in[4];
    const float* A_log    = (const float*)d_in[5];
    const float* D_param  = (const float*)d_in[6];
    const float* norm_w   = (const float*)d_in[7];
    const float* w_out    = (const float*)d_in[8];
    float* out = (float*)d_out;

    const size_t sz_zf  = (size_t)TTOK * D_INNER * 2;     // 33,554,432 (f16)
    const size_t sz_cb  = (size_t)TTOK * XBC_DIM * 2;     // 34,603,008 (f16)
    const size_t sz_x16 = (size_t)TTOK * D_MODEL * 2;     // 16,777,216
    const size_t sz_wi  = (size_t)N_ZX * D_MODEL * 2;     // 34,078,720
    const size_t sz_wo  = (size_t)D_MODEL * D_INNER * 2;  // 16,777,216
    const size_t sz_bc  = (size_t)TTOK * 128 * 4;         //  2,097,152
    const size_t sz_dt  = (size_t)TTOK * 64 * 4;          //  1,048,576
    const size_t sz_acs = (size_t)128 * LSEQ * 4;         //  1,048,576
    const size_t sz_st  = (size_t)1024 * 4096 * 4;        // 16,777,216
    const size_t need = sz_zf + sz_cb + sz_x16 + sz_wi + sz_wo
                      + sz_bc + sz_dt + sz_acs + sz_st;   // 156,762,112 (< proven 157,286,400)
    if (ws_size < need) return;

    char* p = (char*)d_ws;
    _Float16* zf     = (_Float16*)p; p += sz_zf;
    _Float16* cbuf   = (_Float16*)p; p += sz_cb;
    _Float16* x16    = (_Float16*)p; p += sz_x16;
    _Float16* win16  = (_Float16*)p; p += sz_wi;
    _Float16* wout16 = (_Float16*)p; p += sz_wo;
    float*    bc     = (float*)p;    p += sz_bc;
    float*    dtb    = (float*)p;    p += sz_dt;
    float*    acs    = (float*)p;    p += sz_acs;
    float*    states = (float*)p;    p += sz_st;
    float* usq  = dtb;   // alias: dt global reads complete (pre-barrier) before usq writes
    float* rstd = acs;   // alias: acs dead after ymerged

    // 0. f32 -> f16 pre-conversions
    cvt16_kernel<<<(TTOK * D_MODEL / 8 + 255) / 256, 256, 0, stream>>>(
        x, x16, (size_t)TTOK * D_MODEL / 8);
    cvt16_kernel<<<((size_t)N_ZX * D_MODEL / 8 + 255) / 256, 256, 0, stream>>>(
        w_in, win16, (size_t)N_ZX * D_MODEL / 8);
    cvt_wout_kernel<<<(D_MODEL * D_INNER / 8 + 255) / 256, 256, 0, stream>>>(
        w_out, norm_w, wout16);

    // 1. merged in_proj (z -> zf f16, conv-in -> cbuf f16)
    gemm_in16<<<dim3(N_ZX / 128, TTOK / 128), 256, 0, stream>>>(x16, win16, zf, cbuf);
    // 2. dt (pure f32)
    dtproj_kernel<<<TTOK / 16, 256, 0, stream>>>(x, w_in, dt_bias, dtb);
    // 3. per-chunk cumsum
    scan_kernel<<<2 * NH, 256, 0, stream>>>(dtb, A_log, acs);
    // 4. convolved B/C
    bcconv_kernel<<<TTOK, 128, 0, stream>>>(cbuf, conv_w, conv_b, bc);
    // 5. chunk states
    chunkstate_kernel<<<2 * NCH * NH, 256, 0, stream>>>(
        cbuf, bc, conv_w, conv_b, dtb, acs, states);
    // 6. inter-chunk recurrence
    chunkscan_kernel<<<2 * NH, 256, 0, stream>>>(acs, states);
    // 7. merged Y + gate (u f16 in-place over z)
    ymerged_mfma<<<2 * NCH * NH, 256, 0, stream>>>(
        cbuf, bc, conv_w, conv_b, zf, dtb, acs, states, D_param, usq);
    // 8. rstd
    rstd_kernel<<<TTOK / 256, 256, 0, stream>>>(usq, rstd);
    // 9. out_proj (u f16 @ wout16, rstd in epilogue)
    gemm_out16<<<dim3(D_MODEL / 128, TTOK / 128), 256, 0, stream>>>(zf, wout16, out, rstd);
}

// Round 12
// 667.588 us; speedup vs baseline: 5.3153x; 1.0421x over previous
//
#include <hip/hip_runtime.h>
#include <math.h>

#define D_MODEL   2048
#define D_INNER   4096
#define XBC_DIM   4224
#define D_IN_PROJ 8384
#define N_ZX      8320
#define NH    64
#define HD    64
#define DS    64
#define LCH   256
#define NCH   8
#define LSEQ  2048
#define TTOK  4096
#define EPS_R 1.1920929e-07f

#define XT_S 264   // XT inner stride (f16 elems)
#define WL_S 72    // W scratch inner stride (f16 elems)

typedef unsigned short u16;
typedef unsigned int   u32;
typedef _Float16 f16x8 __attribute__((ext_vector_type(8)));
typedef _Float16 f16x4 __attribute__((ext_vector_type(4)));
typedef float    f4v   __attribute__((ext_vector_type(4)));

__device__ __forceinline__ float4 f16_ld4(const _Float16* c, size_t idx) {
    f16x4 v = *(const f16x4*)(c + idx);
    return make_float4((float)v[0], (float)v[1], (float)v[2], (float)v[3]);
}
__device__ __forceinline__ f16x8 cvt8(float4 a, float4 b) {
    f16x8 r;
    r[0] = (_Float16)a.x; r[1] = (_Float16)a.y; r[2] = (_Float16)a.z; r[3] = (_Float16)a.w;
    r[4] = (_Float16)b.x; r[5] = (_Float16)b.y; r[6] = (_Float16)b.z; r[7] = (_Float16)b.w;
    return r;
}
__device__ __forceinline__ float fexp(float x)  { return __expf(x); }
__device__ __forceinline__ float fsilu(float x) { return x / (1.f + __expf(-x)); }
// bijective XCD swizzle: nwg must be divisible by 8 (m204)
__device__ __forceinline__ int xcd_swz(int orig, int nwg) {
    int cpx = nwg >> 3;
    return (orig & 7) * cpx + (orig >> 3);
}

// ---- one-time f32 -> f16 conversions ------------------------------------
__global__ __launch_bounds__(256) void cvt16_kernel(const float* __restrict__ src,
                                                    _Float16* __restrict__ dst,
                                                    size_t n8) {
    size_t i = (size_t)blockIdx.x * 256 + threadIdx.x;
    if (i >= n8) return;
    float4 a = *(const float4*)(src + i * 8);
    float4 b = *(const float4*)(src + i * 8 + 4);
    *(f16x8*)(dst + i * 8) = cvt8(a, b);
}
__global__ __launch_bounds__(256) void cvt_wout_kernel(const float* __restrict__ w,
                                                       const float* __restrict__ nw,
                                                       _Float16* __restrict__ dst) {
    size_t i = (size_t)blockIdx.x * 256 + threadIdx.x;
    size_t base = i * 8;
    int k = (int)(base & 4095);
    float4 a = *(const float4*)(w + base);
    float4 b = *(const float4*)(w + base + 4);
    float4 na = *(const float4*)(nw + k);
    float4 nb = *(const float4*)(nw + k + 4);
    a.x *= na.x; a.y *= na.y; a.z *= na.z; a.w *= na.w;
    b.x *= nb.x; b.y *= nb.y; b.z *= nb.z; b.w *= nb.w;
    *(f16x8*)(dst + base) = cvt8(a, b);
}

// ===== pure-f16 MFMA GEMM, BK=64, 128x128 tile, XCD-swizzled grid ========
__global__ __launch_bounds__(256) void gemm_in16(const _Float16* __restrict__ A,
                                                 const _Float16* __restrict__ W,
                                                 _Float16* __restrict__ zf,
                                                 _Float16* __restrict__ cbuf) {
    __shared__ __align__(16) _Float16 lsA[128][72];
    __shared__ __align__(16) _Float16 lsB[128][72];
    const int tid = threadIdx.x;
    int swz = xcd_swz(blockIdx.x, (N_ZX / 128) * (TTOK / 128));
    const int row0 = (swz / (N_ZX / 128)) * 128, col0 = (swz % (N_ZX / 128)) * 128;
    const int lane = tid & 63, wv = tid >> 6;
    const int wr = wv >> 1, wc = wv & 1;
    const int fr = lane & 15, fq = lane >> 4;

    f4v acc[4][4];
    #pragma unroll
    for (int mi = 0; mi < 4; ++mi)
        #pragma unroll
        for (int ni = 0; ni < 4; ++ni) acc[mi][ni] = (f4v){0.f, 0.f, 0.f, 0.f};

    for (int k0 = 0; k0 < D_MODEL; k0 += 64) {
        #pragma unroll
        for (int i = 0; i < 4; ++i) {
            int idx = tid + i * 256;
            int r = idx >> 3, kc = (idx & 7) * 8;
            *(f16x8*)&lsA[r][kc] = *(const f16x8*)(A + (size_t)(row0 + r) * D_MODEL + k0 + kc);
            *(f16x8*)&lsB[r][kc] = *(const f16x8*)(W + (size_t)(col0 + r) * D_MODEL + k0 + kc);
        }
        __syncthreads();
        f16x8 ah[4][2];
        #pragma unroll
        for (int mi = 0; mi < 4; ++mi)
            #pragma unroll
            for (int kf = 0; kf < 2; ++kf)
                ah[mi][kf] = *(const f16x8*)&lsA[wr * 64 + mi * 16 + fr][kf * 32 + fq * 8];
        #pragma unroll
        for (int ni = 0; ni < 4; ++ni) {
            #pragma unroll
            for (int kf = 0; kf < 2; ++kf) {
                f16x8 bh = *(const f16x8*)&lsB[wc * 64 + ni * 16 + fr][kf * 32 + fq * 8];
                #pragma unroll
                for (int mi = 0; mi < 4; ++mi)
                    acc[mi][ni] = __builtin_amdgcn_mfma_f32_16x16x32_f16(ah[mi][kf], bh, acc[mi][ni], 0, 0, 0);
            }
        }
        __syncthreads();
    }

    const int orow = fq * 4;
    #pragma unroll
    for (int mi = 0; mi < 4; ++mi)
        #pragma unroll
        for (int ni = 0; ni < 4; ++ni) {
            int r = row0 + wr * 64 + mi * 16 + orow;
            int cc = col0 + wc * 64 + ni * 16 + fr;
            if (col0 < D_INNER) {
                #pragma unroll
                for (int j = 0; j < 4; ++j)
                    zf[(size_t)(r + j) * D_INNER + cc] = (_Float16)acc[mi][ni][j];
            } else {
                #pragma unroll
                for (int j = 0; j < 4; ++j)
                    cbuf[(size_t)(r + j) * XBC_DIM + (cc - D_INNER)] = (_Float16)acc[mi][ni][j];
            }
        }
}

__global__ __launch_bounds__(256) void gemm_out16(const _Float16* __restrict__ A,
                                                  const _Float16* __restrict__ W,
                                                  float* __restrict__ C,
                                                  const float* __restrict__ rstd) {
    __shared__ __align__(16) _Float16 lsA[128][72];
    __shared__ __align__(16) _Float16 lsB[128][72];
    const int tid = threadIdx.x;
    int swz = xcd_swz(blockIdx.x, (D_MODEL / 128) * (TTOK / 128));
    const int row0 = (swz / (D_MODEL / 128)) * 128, col0 = (swz % (D_MODEL / 128)) * 128;
    const int lane = tid & 63, wv = tid >> 6;
    const int wr = wv >> 1, wc = wv & 1;
    const int fr = lane & 15, fq = lane >> 4;

    f4v acc[4][4];
    #pragma unroll
    for (int mi = 0; mi < 4; ++mi)
        #pragma unroll
        for (int ni = 0; ni < 4; ++ni) acc[mi][ni] = (f4v){0.f, 0.f, 0.f, 0.f};

    for (int k0 = 0; k0 < D_INNER; k0 += 64) {
        #pragma unroll
        for (int i = 0; i < 4; ++i) {
            int idx = tid + i * 256;
            int r = idx >> 3, kc = (idx & 7) * 8;
            *(f16x8*)&lsA[r][kc] = *(const f16x8*)(A + (size_t)(row0 + r) * D_INNER + k0 + kc);
            *(f16x8*)&lsB[r][kc] = *(const f16x8*)(W + (size_t)(col0 + r) * D_INNER + k0 + kc);
        }
        __syncthreads();
        f16x8 ah[4][2];
        #pragma unroll
        for (int mi = 0; mi < 4; ++mi)
            #pragma unroll
            for (int kf = 0; kf < 2; ++kf)
                ah[mi][kf] = *(const f16x8*)&lsA[wr * 64 + mi * 16 + fr][kf * 32 + fq * 8];
        #pragma unroll
        for (int ni = 0; ni < 4; ++ni) {
            #pragma unroll
            for (int kf = 0; kf < 2; ++kf) {
                f16x8 bh = *(const f16x8*)&lsB[wc * 64 + ni * 16 + fr][kf * 32 + fq * 8];
                #pragma unroll
                for (int mi = 0; mi < 4; ++mi)
                    acc[mi][ni] = __builtin_amdgcn_mfma_f32_16x16x32_f16(ah[mi][kf], bh, acc[mi][ni], 0, 0, 0);
            }
        }
        __syncthreads();
    }

    const int orow = fq * 4;
    #pragma unroll
    for (int mi = 0; mi < 4; ++mi)
        #pragma unroll
        for (int ni = 0; ni < 4; ++ni) {
            int r = row0 + wr * 64 + mi * 16 + orow;
            int cc = col0 + wc * 64 + ni * 16 + fr;
            #pragma unroll
            for (int j = 0; j < 4; ++j)
                C[(size_t)(r + j) * D_MODEL + cc] = acc[mi][ni][j] * rstd[r + j];
        }
}

// ----- dt projection in pure f32 (precise libm: dt is exp-amplified) -----
__global__ __launch_bounds__(256) void dtproj_kernel(const float* __restrict__ x,
                                                     const float* __restrict__ w_in,
                                                     const float* __restrict__ dt_bias,
                                                     float* __restrict__ dt_buf) {
    __shared__ float Xs[16][64];
    __shared__ float Ws[64][65];
    int tid = threadIdx.x;
    int t0 = blockIdx.x * 16;
    int h = tid & 63, trow = tid >> 6;
    float acc[4] = {0.f, 0.f, 0.f, 0.f};
    const float* wdt = w_in + (size_t)(D_INNER + XBC_DIM) * D_MODEL;

    for (int k0 = 0; k0 < D_MODEL; k0 += 64) {
        __syncthreads();
        {
            int r = tid >> 4, c4 = (tid & 15) * 4;
            *(float4*)&Xs[r][c4] = *(const float4*)(x + (size_t)(t0 + r) * D_MODEL + k0 + c4);
        }
        #pragma unroll
        for (int i = 0; i < 4; ++i) {
            int ff = tid + i * 256;
            int r = ff >> 4, c4 = (ff & 15) * 4;
            float4 v = *(const float4*)(wdt + (size_t)r * D_MODEL + k0 + c4);
            Ws[r][c4 + 0] = v.x; Ws[r][c4 + 1] = v.y;
            Ws[r][c4 + 2] = v.z; Ws[r][c4 + 3] = v.w;
        }
        __syncthreads();
        #pragma unroll 16
        for (int k = 0; k < 64; ++k) {
            float wv = Ws[h][k];
            #pragma unroll
            for (int i = 0; i < 4; ++i)
                acc[i] += Xs[trow + i * 4][k] * wv;
        }
    }
    float bias = dt_bias[h];
    #pragma unroll
    for (int i = 0; i < 4; ++i) {
        float xv = acc[i] + bias;
        float sp = (xv > 20.f) ? xv : log1pf(expf(xv));
        dt_buf[(size_t)(t0 + trow + i * 4) * 64 + h] = sp;
    }
}

// ------------- per-(b,h) chunk-local inclusive cumsum of a=A*dt ----------
__global__ __launch_bounds__(256) void scan_kernel(const float* __restrict__ dt_buf,
                                                   const float* __restrict__ A_log,
                                                   float* __restrict__ acs) {
    int b = blockIdx.x >> 6, h = blockIdx.x & 63;
    float Ah = -expf(A_log[h]);
    __shared__ float s[256];
    int tid = threadIdx.x;
    for (int c = 0; c < NCH; ++c) {
        int t = b * LSEQ + c * LCH + tid;
        float a = Ah * dt_buf[t * 64 + h];
        s[tid] = a;
        __syncthreads();
        for (int off = 1; off < 256; off <<= 1) {
            float v = (tid >= off) ? s[tid - off] : 0.f;
            __syncthreads();
            s[tid] += v;
            __syncthreads();
        }
        acs[(size_t)blockIdx.x * LSEQ + c * LCH + tid] = s[tid];
        __syncthreads();
    }
}

// ---- convolved B/C (128 channels) in f32 --------------------------------
__global__ __launch_bounds__(128) void bcconv_kernel(const _Float16* __restrict__ cbuf,
                                                     const float* __restrict__ cw,
                                                     const float* __restrict__ cb,
                                                     float* __restrict__ bc) {
    int chl = threadIdx.x;
    int t = blockIdx.x;
    int b = t >> 11, lp = t & 2047;
    int ch = D_INNER + chl;
    float acc = cb[ch];
    #pragma unroll
    for (int j = 0; j < 4; ++j) {
        int lj = lp - 3 + j;
        if (lj >= 0)
            acc += cw[ch * 4 + j] * (float)cbuf[(size_t)(b * LSEQ + lj) * XBC_DIM + ch];
    }
    bc[(size_t)t * 128 + chl] = fsilu(acc);
}

// ===== MFMA chunk states: states[p][n] = sum_s Xw^T[p,s] · B^T[n,s] ======
// Xw = dec·dt·silu(conv(X)); A-frags from conv-fused weighted X^T staging,
// B-frags from bc transposed into LDS. 32 MFMAs/wave, f32 out.
__global__ __launch_bounds__(256) void chunkstate_mfma(const _Float16* __restrict__ cbuf,
                                                       const float* __restrict__ bc,
                                                       const float* __restrict__ cw,
                                                       const float* __restrict__ cb,
                                                       const float* __restrict__ dt_buf,
                                                       const float* __restrict__ acs,
                                                       float* __restrict__ states) {
    const int h = blockIdx.x & 63;
    const int c = (blockIdx.x >> 6) & 7;
    const int b = blockIdx.x >> 9;
    const int tbase = b * LSEQ + c * LCH;
    const int tid = threadIdx.x, lane = tid & 63, w = tid >> 6;
    const int fr = lane & 15, fq = lane >> 4;

    __shared__ __align__(16) _Float16 XTw[64][XT_S];  // weighted X^T [p][s]
    __shared__ __align__(16) _Float16 BT[64][XT_S];   // B^T [n][s]
    __shared__ float acs_s[256], dts[256];

    const float* acs_blk = acs + (size_t)(b * 64 + h) * LSEQ + c * LCH;
    acs_s[tid] = acs_blk[tid];
    dts[tid] = dt_buf[(size_t)(tbase + tid) * 64 + h];
    __syncthreads();
    const float acs_last = acs_s[LCH - 1];

    // stage XTw (conv + silu, weighted by dec*dt, f16)
    #pragma unroll 4
    for (int i = 0; i < 16; ++i) {
        int u = tid + i * 256;
        int s = u >> 4, pq = (u & 15) * 4;
        float wdec = fexp(acs_last - acs_s[s]) * dts[s];
        int lp = c * LCH + s;
        int ch0 = h * HD + pq;
        float tp[4][4];
        #pragma unroll
        for (int k = 0; k < 4; ++k)
            *(float4*)tp[k] = *(const float4*)(cw + (size_t)(ch0 + k) * 4);
        float a0 = cb[ch0], a1 = cb[ch0 + 1], a2 = cb[ch0 + 2], a3 = cb[ch0 + 3];
        #pragma unroll
        for (int j = 0; j < 4; ++j) {
            int lj = lp - 3 + j;
            if (lj >= 0) {
                float4 v = f16_ld4(cbuf, (size_t)(b * LSEQ + lj) * XBC_DIM + ch0);
                a0 += tp[0][j] * v.x; a1 += tp[1][j] * v.y;
                a2 += tp[2][j] * v.z; a3 += tp[3][j] * v.w;
            }
        }
        XTw[pq + 0][s] = (_Float16)(fsilu(a0) * wdec);
        XTw[pq + 1][s] = (_Float16)(fsilu(a1) * wdec);
        XTw[pq + 2][s] = (_Float16)(fsilu(a2) * wdec);
        XTw[pq + 3][s] = (_Float16)(fsilu(a3) * wdec);
    }
    // stage BT[n][s] from bc (f32 -> f16, transposed)
    #pragma unroll 4
    for (int i = 0; i < 16; ++i) {
        int u = tid + i * 256;
        int s = u >> 4, n4 = (u & 15) * 4;
        float4 v = *(const float4*)(bc + (size_t)(tbase + s) * 128 + n4);
        BT[n4 + 0][s] = (_Float16)v.x; BT[n4 + 1][s] = (_Float16)v.y;
        BT[n4 + 2][s] = (_Float16)v.z; BT[n4 + 3][s] = (_Float16)v.w;
    }
    __syncthreads();

    f4v acc[4];
    #pragma unroll
    for (int nf = 0; nf < 4; ++nf) acc[nf] = (f4v){0.f, 0.f, 0.f, 0.f};
    #pragma unroll
    for (int ks = 0; ks < 8; ++ks) {
        f16x8 af = *(const f16x8*)&XTw[w * 16 + fr][ks * 32 + fq * 8];
        #pragma unroll
        for (int nf = 0; nf < 4; ++nf) {
            f16x8 bf = *(const f16x8*)&BT[nf * 16 + fr][ks * 32 + fq * 8];
            acc[nf] = __builtin_amdgcn_mfma_f32_16x16x32_f16(af, bf, acc[nf], 0, 0, 0);
        }
    }
    // C/D: col = fr (n), row = fq*4 + r (p within 16)
    float* sp = states + (size_t)blockIdx.x * 4096;
    #pragma unroll
    for (int nf = 0; nf < 4; ++nf)
        #pragma unroll
        for (int r = 0; r < 4; ++r)
            sp[(size_t)(w * 16 + fq * 4 + r) * 64 + nf * 16 + fr] = acc[nf][r];
}

// ----- inter-chunk recurrence per (b,h); in-place ------------------------
__global__ __launch_bounds__(256) void chunkscan_kernel(const float* __restrict__ acs,
                                                        float* __restrict__ states) {
    int b = blockIdx.x >> 6, h = blockIdx.x & 63;
    int tid = threadIdx.x;
    float4 S4[4];
    #pragma unroll
    for (int i = 0; i < 4; ++i) S4[i] = make_float4(0.f, 0.f, 0.f, 0.f);
    const float* acs_blk = acs + (size_t)blockIdx.x * LSEQ;
    for (int c = 0; c < NCH; ++c) {
        float d = expf(acs_blk[c * LCH + LCH - 1]);
        float4* sp = (float4*)(states + ((size_t)(b * NCH + c) * NH + h) * 4096 + tid * 16);
        float4 t4[4];
        #pragma unroll
        for (int i = 0; i < 4; ++i) t4[i] = sp[i];
        #pragma unroll
        for (int i = 0; i < 4; ++i) sp[i] = S4[i];
        #pragma unroll
        for (int i = 0; i < 4; ++i) {
            S4[i].x = d * S4[i].x + t4[i].x;
            S4[i].y = d * S4[i].y + t4[i].y;
            S4[i].z = d * S4[i].z + t4[i].z;
            S4[i].w = d * S4[i].w + t4[i].w;
        }
    }
}

// ===== MFMA ymerged: Y = Yoff + Ydiag + X·D; u = z·silu(Y), z/u f16 ======
__global__ __launch_bounds__(256) void ymerged_mfma(const _Float16* __restrict__ cbuf,
                                                    const float* __restrict__ bc,
                                                    const float* __restrict__ cw,
                                                    const float* __restrict__ cb,
                                                    _Float16* __restrict__ zf,
                                                    const float* __restrict__ dt_buf,
                                                    const float* __restrict__ acs,
                                                    const float* __restrict__ states,
                                                    const float* __restrict__ D_param,
                                                    float* __restrict__ usq) {
    const int h = blockIdx.x & 63;
    const int c = (blockIdx.x >> 6) & 7;
    const int b = blockIdx.x >> 9;
    const int tbase = b * LSEQ + c * LCH;
    const int tid = threadIdx.x, lane = tid & 63, w = tid >> 6;
    const int fr = lane & 15, fq = lane >> 4;

    __shared__ __align__(16) _Float16 XT[64][XT_S];      // X^T [p][s]
    __shared__ __align__(16) _Float16 Wl[4][64][WL_S];   // per-wave W scratch
    __shared__ float acs_s[256];
    __shared__ float dts[256];

    const float* acs_blk = acs + (size_t)(b * 64 + h) * LSEQ + c * LCH;
    acs_s[tid] = acs_blk[tid];
    dts[tid] = dt_buf[(size_t)(tbase + tid) * 64 + h];

    // ---- stage X^T (conv + silu, f32 math, f16 store) ----
    #pragma unroll 4
    for (int i = 0; i < 16; ++i) {
        int u = tid + i * 256;
        int s = u >> 4, pq = (u & 15) * 4;
        int lp = c * LCH + s;
        int ch0 = h * HD + pq;
        float tp[4][4];
        #pragma unroll
        for (int k = 0; k < 4; ++k)
            *(float4*)tp[k] = *(const float4*)(cw + (size_t)(ch0 + k) * 4);
        float a0 = cb[ch0], a1 = cb[ch0 + 1], a2 = cb[ch0 + 2], a3 = cb[ch0 + 3];
        #pragma unroll
        for (int j = 0; j < 4; ++j) {
            int lj = lp - 3 + j;
            if (lj >= 0) {
                float4 v = f16_ld4(cbuf, (size_t)(b * LSEQ + lj) * XBC_DIM + ch0);
                a0 += tp[0][j] * v.x; a1 += tp[1][j] * v.y;
                a2 += tp[2][j] * v.z; a3 += tp[3][j] * v.w;
            }
        }
        XT[pq + 0][s] = (_Float16)fsilu(a0);
        XT[pq + 1][s] = (_Float16)fsilu(a1);
        XT[pq + 2][s] = (_Float16)fsilu(a2);
        XT[pq + 3][s] = (_Float16)fsilu(a3);
    }
    __syncthreads();

    // ---- C fragments ----
    f16x8 cf[4][2];
    #pragma unroll
    for (int ls = 0; ls < 4; ++ls)
        #pragma unroll
        for (int kf = 0; kf < 2; ++kf) {
            const float* src = bc + (size_t)(tbase + w * 64 + ls * 16 + fr) * 128
                             + 64 + kf * 32 + fq * 8;
            cf[ls][kf] = cvt8(*(const float4*)src, *(const float4*)(src + 4));
        }

    float acsl[16];
    #pragma unroll
    for (int ls = 0; ls < 4; ++ls)
        #pragma unroll
        for (int r = 0; r < 4; ++r)
            acsl[ls * 4 + r] = acs_s[w * 64 + ls * 16 + fq * 4 + r];

    f4v Y[4][4];
    // ---- Y_off = e_l · C @ Sin^T ----
    {
        f16x8 sf[4][2];
        #pragma unroll
        for (int ps = 0; ps < 4; ++ps)
            #pragma unroll
            for (int kf = 0; kf < 2; ++kf) {
                const float* src = states + (size_t)blockIdx.x * 4096
                                 + (ps * 16 + fr) * 64 + kf * 32 + fq * 8;
                sf[ps][kf] = cvt8(*(const float4*)src, *(const float4*)(src + 4));
            }
        f4v yo[4][4];
        #pragma unroll
        for (int ls = 0; ls < 4; ++ls)
            #pragma unroll
            for (int ps = 0; ps < 4; ++ps) {
                yo[ls][ps] = (f4v){0.f, 0.f, 0.f, 0.f};
                yo[ls][ps] = __builtin_amdgcn_mfma_f32_16x16x32_f16(cf[ls][0], sf[ps][0], yo[ls][ps], 0, 0, 0);
                yo[ls][ps] = __builtin_amdgcn_mfma_f32_16x16x32_f16(cf[ls][1], sf[ps][1], yo[ls][ps], 0, 0, 0);
            }
        #pragma unroll
        for (int ls = 0; ls < 4; ++ls)
            #pragma unroll
            for (int ps = 0; ps < 4; ++ps)
                #pragma unroll
                for (int r = 0; r < 4; ++r)
                    Y[ls][ps][r] = fexp(acsl[ls * 4 + r]) * yo[ls][ps][r];
    }

    // ---- Y_diag: s-tiles 0..w ----
    for (int st = 0; st <= w; ++st) {
        f16x8 bf[4][2];
        #pragma unroll
        for (int ss = 0; ss < 4; ++ss)
            #pragma unroll
            for (int kf = 0; kf < 2; ++kf) {
                const float* src = bc + (size_t)(tbase + st * 64 + ss * 16 + fr) * 128
                                 + kf * 32 + fq * 8;
                bf[ss][kf] = cvt8(*(const float4*)src, *(const float4*)(src + 4));
            }
        f4v S[4][4];
        #pragma unroll
        for (int ls = 0; ls < 4; ++ls)
            #pragma unroll
            for (int ss = 0; ss < 4; ++ss) {
                S[ls][ss] = (f4v){0.f, 0.f, 0.f, 0.f};
                S[ls][ss] = __builtin_amdgcn_mfma_f32_16x16x32_f16(cf[ls][0], bf[ss][0], S[ls][ss], 0, 0, 0);
                S[ls][ss] = __builtin_amdgcn_mfma_f32_16x16x32_f16(cf[ls][1], bf[ss][1], S[ls][ss], 0, 0, 0);
            }
        #pragma unroll
        for (int ss = 0; ss < 4; ++ss) {
            int s_idx = st * 64 + ss * 16 + fr;
            float as = acs_s[s_idx];
            float dv = dts[s_idx];
            #pragma unroll
            for (int ls = 0; ls < 4; ++ls)
                #pragma unroll
                for (int r = 0; r < 4; ++r) {
                    int l_idx = w * 64 + ls * 16 + fq * 4 + r;
                    float wv = (s_idx <= l_idx)
                             ? fexp(acsl[ls * 4 + r] - as) * dv * S[ls][ss][r] : 0.f;
                    Wl[w][ls * 16 + fq * 4 + r][ss * 16 + fr] = (_Float16)wv;
                }
        }
        f16x8 wf[4][2], xf[4][2];
        #pragma unroll
        for (int ls = 0; ls < 4; ++ls)
            #pragma unroll
            for (int kf = 0; kf < 2; ++kf)
                wf[ls][kf] = *(const f16x8*)&Wl[w][ls * 16 + fr][kf * 32 + fq * 8];
        #pragma unroll
        for (int ps = 0; ps < 4; ++ps)
            #pragma unroll
            for (int kf = 0; kf < 2; ++kf)
                xf[ps][kf] = *(const f16x8*)&XT[ps * 16 + fr][st * 64 + kf * 32 + fq * 8];
        #pragma unroll
        for (int ls = 0; ls < 4; ++ls)
            #pragma unroll
            for (int ps = 0; ps < 4; ++ps) {
                Y[ls][ps] = __builtin_amdgcn_mfma_f32_16x16x32_f16(wf[ls][0], xf[ps][0], Y[ls][ps], 0, 0, 0);
                Y[ls][ps] = __builtin_amdgcn_mfma_f32_16x16x32_f16(wf[ls][1], xf[ps][1], Y[ls][ps], 0, 0, 0);
            }
    }

    // ---- D-term + gate + usq (z/u f16) ----
    float Dp = D_param[h];
    #pragma unroll
    for (int ls = 0; ls < 4; ++ls)
        #pragma unroll
        for (int r = 0; r < 4; ++r) {
            int l = w * 64 + ls * 16 + fq * 4 + r;
            int tl = tbase + l;
            float ss_acc = 0.f;
            #pragma unroll
            for (int ps = 0; ps < 4; ++ps) {
                int p = ps * 16 + fr;
                float y = Y[ls][ps][r] + (float)XT[p][l] * Dp;
                _Float16* zp = zf + (size_t)tl * D_INNER + h * HD + p;
                float uv = (float)(*zp) * fsilu(y);
                *zp = (_Float16)uv;
                ss_acc += uv * uv;
            }
            ss_acc += __shfl_xor(ss_acc, 1);
            ss_acc += __shfl_xor(ss_acc, 2);
            ss_acc += __shfl_xor(ss_acc, 4);
            ss_acc += __shfl_xor(ss_acc, 8);
            if (fr == 0) usq[(size_t)tl * 64 + h] = ss_acc;
        }
}

// ----- rstd[t] = rsqrt(mean(u^2) + eps) ----------------------------------
__global__ __launch_bounds__(256) void rstd_kernel(const float* __restrict__ usq,
                                                   float* __restrict__ rstd) {
    int t = blockIdx.x * 256 + threadIdx.x;
    float s = 0.f;
    #pragma unroll
    for (int i = 0; i < 16; ++i) {
        float4 v = *(const float4*)(usq + (size_t)t * 64 + i * 4);
        s += v.x + v.y + v.z + v.w;
    }
    rstd[t] = rsqrtf(s / 4096.f + EPS_R);
}

extern "C" void kernel_launch(void* const* d_in, const int* in_sizes, int n_in,
                              void* d_out, int out_size, void* d_ws, size_t ws_size,
                              hipStream_t stream) {
    const float* x        = (const float*)d_in[0];
    const float* w_in     = (const float*)d_in[1];
    const float* conv_w   = (const float*)d_in[2];
    const float* conv_b   = (const float*)d_in[3];
    const float* dt_bias  = (const float*)d_in[4];
    const float* A_log    = (const float*)d_in[5];
    const float* D_param  = (const float*)d_in[6];
    const float* norm_w   = (const float*)d_in[7];
    const float* w_out    = (const float*)d_in[8];
    float* out = (float*)d_out;

    const size_t sz_zf  = (size_t)TTOK * D_INNER * 2;     // 33,554,432 (f16)
    const size_t sz_cb  = (size_t)TTOK * XBC_DIM * 2;     // 34,603,008 (f16)
    const size_t sz_x16 = (size_t)TTOK * D_MODEL * 2;     // 16,777,216
    const size_t sz_wi  = (size_t)N_ZX * D_MODEL * 2;     // 34,078,720
    const size_t sz_wo  = (size_t)D_MODEL * D_INNER * 2;  // 16,777,216
    const size_t sz_bc  = (size_t)TTOK * 128 * 4;         //  2,097,152
    const size_t sz_dt  = (size_t)TTOK * 64 * 4;          //  1,048,576
    const size_t sz_acs = (size_t)128 * LSEQ * 4;         //  1,048,576
    const size_t sz_st  = (size_t)1024 * 4096 * 4;        // 16,777,216
    const size_t need = sz_zf + sz_cb + sz_x16 + sz_wi + sz_wo
                      + sz_bc + sz_dt + sz_acs + sz_st;   // 156,762,112
    if (ws_size < need) return;

    char* p = (char*)d_ws;
    _Float16* zf     = (_Float16*)p; p += sz_zf;
    _Float16* cbuf   = (_Float16*)p; p += sz_cb;
    _Float16* x16    = (_Float16*)p; p += sz_x16;
    _Float16* win16  = (_Float16*)p; p += sz_wi;
    _Float16* wout16 = (_Float16*)p; p += sz_wo;
    float*    bc     = (float*)p;    p += sz_bc;
    float*    dtb    = (float*)p;    p += sz_dt;
    float*    acs    = (float*)p;    p += sz_acs;
    float*    states = (float*)p;    p += sz_st;
    float* usq  = dtb;
    float* rstd = acs;

    cvt16_kernel<<<(TTOK * D_MODEL / 8 + 255) / 256, 256, 0, stream>>>(
        x, x16, (size_t)TTOK * D_MODEL / 8);
    cvt16_kernel<<<((size_t)N_ZX * D_MODEL / 8 + 255) / 256, 256, 0, stream>>>(
        w_in, win16, (size_t)N_ZX * D_MODEL / 8);
    cvt_wout_kernel<<<(D_MODEL * D_INNER / 8 + 255) / 256, 256, 0, stream>>>(
        w_out, norm_w, wout16);

    gemm_in16<<<(N_ZX / 128) * (TTOK / 128), 256, 0, stream>>>(x16, win16, zf, cbuf);
    dtproj_kernel<<<TTOK / 16, 256, 0, stream>>>(x, w_in, dt_bias, dtb);
    scan_kernel<<<2 * NH, 256, 0, stream>>>(dtb, A_log, acs);
    bcconv_kernel<<<TTOK, 128, 0, stream>>>(cbuf, conv_w, conv_b, bc);
    chunkstate_mfma<<<2 * NCH * NH, 256, 0, stream>>>(
        cbuf, bc, conv_w, conv_b, dtb, acs, states);
    chunkscan_kernel<<<2 * NH, 256, 0, stream>>>(acs, states);
    ymerged_mfma<<<2 * NCH * NH, 256, 0, stream>>>(
        cbuf, bc, conv_w, conv_b, zf, dtb, acs, states, D_param, usq);
    rstd_kernel<<<TTOK / 256, 256, 0, stream>>>(usq, rstd);
    gemm_out16<<<(D_MODEL / 128) * (TTOK / 128), 256, 0, stream>>>(zf, wout16, out, rstd);
}

// Round 13
// 641.746 us; speedup vs baseline: 5.5294x; 1.0403x over previous
//
#include <hip/hip_runtime.h>
#include <math.h>

#define D_MODEL   2048
#define D_INNER   4096
#define XBC_DIM   4224
#define D_IN_PROJ 8384
#define N_ZX      8320
#define NH    64
#define HD    64
#define DS    64
#define LCH   256
#define NCH   8
#define LSEQ  2048
#define TTOK  4096
#define EPS_R 1.1920929e-07f

#define XT_S 264   // XT inner stride (f16 elems)
#define WL_S 72    // W scratch inner stride (f16 elems)

typedef unsigned short u16;
typedef unsigned int   u32;
typedef _Float16 f16x8 __attribute__((ext_vector_type(8)));
typedef _Float16 f16x4 __attribute__((ext_vector_type(4)));
typedef float    f4v   __attribute__((ext_vector_type(4)));

__device__ __forceinline__ float4 f16_ld4(const _Float16* c, size_t idx) {
    f16x4 v = *(const f16x4*)(c + idx);
    return make_float4((float)v[0], (float)v[1], (float)v[2], (float)v[3]);
}
__device__ __forceinline__ f16x8 cvt8(float4 a, float4 b) {
    f16x8 r;
    r[0] = (_Float16)a.x; r[1] = (_Float16)a.y; r[2] = (_Float16)a.z; r[3] = (_Float16)a.w;
    r[4] = (_Float16)b.x; r[5] = (_Float16)b.y; r[6] = (_Float16)b.z; r[7] = (_Float16)b.w;
    return r;
}
__device__ __forceinline__ float fexp(float x)  { return __expf(x); }
__device__ __forceinline__ float fsilu(float x) { return x / (1.f + __expf(-x)); }
__device__ __forceinline__ int xcd_swz(int orig, int nwg) {
    int cpx = nwg >> 3;
    return (orig & 7) * cpx + (orig >> 3);
}
// async global->LDS, 16B per lane; lds base must be wave-uniform (m104)
__device__ __forceinline__ void gload16(const _Float16* g, _Float16* l) {
    __builtin_amdgcn_global_load_lds(
        (const __attribute__((address_space(1))) u32*)g,
        (__attribute__((address_space(3))) u32*)l, 16, 0, 0);
}

// ---- one-time f32 -> f16 conversions ------------------------------------
__global__ __launch_bounds__(256) void cvt16_kernel(const float* __restrict__ src,
                                                    _Float16* __restrict__ dst,
                                                    size_t n8) {
    size_t i = (size_t)blockIdx.x * 256 + threadIdx.x;
    if (i >= n8) return;
    float4 a = *(const float4*)(src + i * 8);
    float4 b = *(const float4*)(src + i * 8 + 4);
    *(f16x8*)(dst + i * 8) = cvt8(a, b);
}
__global__ __launch_bounds__(256) void cvt_wout_kernel(const float* __restrict__ w,
                                                       const float* __restrict__ nw,
                                                       _Float16* __restrict__ dst) {
    size_t i = (size_t)blockIdx.x * 256 + threadIdx.x;
    size_t base = i * 8;
    int k = (int)(base & 4095);
    float4 a = *(const float4*)(w + base);
    float4 b = *(const float4*)(w + base + 4);
    float4 na = *(const float4*)(nw + k);
    float4 nb = *(const float4*)(nw + k + 4);
    a.x *= na.x; a.y *= na.y; a.z *= na.z; a.w *= na.w;
    b.x *= nb.x; b.y *= nb.y; b.z *= nb.z; b.w *= nb.w;
    *(f16x8*)(dst + base) = cvt8(a, b);
}

// ===== f16 MFMA GEMM, BK=64, 128x128, global_load_lds + XOR swizzle ======
// LDS linear [128][64] f16 (128 B rows). Stage: pre-swizzled global source
// lb = b0 ^ ((row&7)<<4); read: same XOR on ds_read addr (involution, m201).
__global__ __launch_bounds__(256) void gemm_in16(const _Float16* __restrict__ A,
                                                 const _Float16* __restrict__ W,
                                                 _Float16* __restrict__ zf,
                                                 _Float16* __restrict__ cbuf) {
    __shared__ __align__(16) _Float16 lsA[128 * 64];
    __shared__ __align__(16) _Float16 lsB[128 * 64];
    const int tid = threadIdx.x, lane = tid & 63, w = tid >> 6;
    int swz = xcd_swz(blockIdx.x, (N_ZX / 128) * (TTOK / 128));
    const int row0 = (swz / (N_ZX / 128)) * 128, col0 = (swz % (N_ZX / 128)) * 128;
    const int wr = w >> 1, wc = w & 1;
    const int fr = lane & 15, fq = lane >> 4;

    f4v acc[4][4];
    #pragma unroll
    for (int mi = 0; mi < 4; ++mi)
        #pragma unroll
        for (int ni = 0; ni < 4; ++ni) acc[mi][ni] = (f4v){0.f, 0.f, 0.f, 0.f};

    for (int k0 = 0; k0 < D_MODEL; k0 += 64) {
        #pragma unroll
        for (int i = 0; i < 4; ++i) {
            int obase = i * 4096 + w * 1024;          // wave-uniform byte offset
            int o = obase + lane * 16;                // this lane's dest byte
            int row = o >> 7, b0 = o & 127;
            int lb = b0 ^ ((row & 7) << 4);           // pre-swizzled source byte
            gload16(A + (size_t)(row0 + row) * D_MODEL + k0 + (lb >> 1), lsA + (obase >> 1));
            gload16(W + (size_t)(col0 + row) * D_MODEL + k0 + (lb >> 1), lsB + (obase >> 1));
        }
        __syncthreads();
        f16x8 ah[4][2];
        #pragma unroll
        for (int mi = 0; mi < 4; ++mi)
            #pragma unroll
            for (int kf = 0; kf < 2; ++kf) {
                int r = wr * 64 + mi * 16 + fr;
                int pb = (kf * 64 + fq * 16) ^ ((r & 7) << 4);
                ah[mi][kf] = *(const f16x8*)((const char*)lsA + r * 128 + pb);
            }
        #pragma unroll
        for (int ni = 0; ni < 4; ++ni) {
            #pragma unroll
            for (int kf = 0; kf < 2; ++kf) {
                int rb = wc * 64 + ni * 16 + fr;
                int pb = (kf * 64 + fq * 16) ^ ((rb & 7) << 4);
                f16x8 bh = *(const f16x8*)((const char*)lsB + rb * 128 + pb);
                #pragma unroll
                for (int mi = 0; mi < 4; ++mi)
                    acc[mi][ni] = __builtin_amdgcn_mfma_f32_16x16x32_f16(ah[mi][kf], bh, acc[mi][ni], 0, 0, 0);
            }
        }
        __syncthreads();
    }

    const int orow = fq * 4;
    #pragma unroll
    for (int mi = 0; mi < 4; ++mi)
        #pragma unroll
        for (int ni = 0; ni < 4; ++ni) {
            int r = row0 + wr * 64 + mi * 16 + orow;
            int cc = col0 + wc * 64 + ni * 16 + fr;
            if (col0 < D_INNER) {
                #pragma unroll
                for (int j = 0; j < 4; ++j)
                    zf[(size_t)(r + j) * D_INNER + cc] = (_Float16)acc[mi][ni][j];
            } else {
                #pragma unroll
                for (int j = 0; j < 4; ++j)
                    cbuf[(size_t)(r + j) * XBC_DIM + (cc - D_INNER)] = (_Float16)acc[mi][ni][j];
            }
        }
}

__global__ __launch_bounds__(256) void gemm_out16(const _Float16* __restrict__ A,
                                                  const _Float16* __restrict__ W,
                                                  float* __restrict__ C,
                                                  const float* __restrict__ rstd) {
    __shared__ __align__(16) _Float16 lsA[128 * 64];
    __shared__ __align__(16) _Float16 lsB[128 * 64];
    const int tid = threadIdx.x, lane = tid & 63, w = tid >> 6;
    int swz = xcd_swz(blockIdx.x, (D_MODEL / 128) * (TTOK / 128));
    const int row0 = (swz / (D_MODEL / 128)) * 128, col0 = (swz % (D_MODEL / 128)) * 128;
    const int wr = w >> 1, wc = w & 1;
    const int fr = lane & 15, fq = lane >> 4;

    f4v acc[4][4];
    #pragma unroll
    for (int mi = 0; mi < 4; ++mi)
        #pragma unroll
        for (int ni = 0; ni < 4; ++ni) acc[mi][ni] = (f4v){0.f, 0.f, 0.f, 0.f};

    for (int k0 = 0; k0 < D_INNER; k0 += 64) {
        #pragma unroll
        for (int i = 0; i < 4; ++i) {
            int obase = i * 4096 + w * 1024;
            int o = obase + lane * 16;
            int row = o >> 7, b0 = o & 127;
            int lb = b0 ^ ((row & 7) << 4);
            gload16(A + (size_t)(row0 + row) * D_INNER + k0 + (lb >> 1), lsA + (obase >> 1));
            gload16(W + (size_t)(col0 + row) * D_INNER + k0 + (lb >> 1), lsB + (obase >> 1));
        }
        __syncthreads();
        f16x8 ah[4][2];
        #pragma unroll
        for (int mi = 0; mi < 4; ++mi)
            #pragma unroll
            for (int kf = 0; kf < 2; ++kf) {
                int r = wr * 64 + mi * 16 + fr;
                int pb = (kf * 64 + fq * 16) ^ ((r & 7) << 4);
                ah[mi][kf] = *(const f16x8*)((const char*)lsA + r * 128 + pb);
            }
        #pragma unroll
        for (int ni = 0; ni < 4; ++ni) {
            #pragma unroll
            for (int kf = 0; kf < 2; ++kf) {
                int rb = wc * 64 + ni * 16 + fr;
                int pb = (kf * 64 + fq * 16) ^ ((rb & 7) << 4);
                f16x8 bh = *(const f16x8*)((const char*)lsB + rb * 128 + pb);
                #pragma unroll
                for (int mi = 0; mi < 4; ++mi)
                    acc[mi][ni] = __builtin_amdgcn_mfma_f32_16x16x32_f16(ah[mi][kf], bh, acc[mi][ni], 0, 0, 0);
            }
        }
        __syncthreads();
    }

    const int orow = fq * 4;
    #pragma unroll
    for (int mi = 0; mi < 4; ++mi)
        #pragma unroll
        for (int ni = 0; ni < 4; ++ni) {
            int r = row0 + wr * 64 + mi * 16 + orow;
            int cc = col0 + wc * 64 + ni * 16 + fr;
            #pragma unroll
            for (int j = 0; j < 4; ++j)
                C[(size_t)(r + j) * D_MODEL + cc] = acc[mi][ni][j] * rstd[r + j];
        }
}

// ----- dt projection in pure f32 (precise libm: dt is exp-amplified) -----
__global__ __launch_bounds__(256) void dtproj_kernel(const float* __restrict__ x,
                                                     const float* __restrict__ w_in,
                                                     const float* __restrict__ dt_bias,
                                                     float* __restrict__ dt_buf) {
    __shared__ float Xs[16][64];
    __shared__ float Ws[64][65];
    int tid = threadIdx.x;
    int t0 = blockIdx.x * 16;
    int h = tid & 63, trow = tid >> 6;
    float acc[4] = {0.f, 0.f, 0.f, 0.f};
    const float* wdt = w_in + (size_t)(D_INNER + XBC_DIM) * D_MODEL;

    for (int k0 = 0; k0 < D_MODEL; k0 += 64) {
        __syncthreads();
        {
            int r = tid >> 4, c4 = (tid & 15) * 4;
            *(float4*)&Xs[r][c4] = *(const float4*)(x + (size_t)(t0 + r) * D_MODEL + k0 + c4);
        }
        #pragma unroll
        for (int i = 0; i < 4; ++i) {
            int ff = tid + i * 256;
            int r = ff >> 4, c4 = (ff & 15) * 4;
            float4 v = *(const float4*)(wdt + (size_t)r * D_MODEL + k0 + c4);
            Ws[r][c4 + 0] = v.x; Ws[r][c4 + 1] = v.y;
            Ws[r][c4 + 2] = v.z; Ws[r][c4 + 3] = v.w;
        }
        __syncthreads();
        #pragma unroll 16
        for (int k = 0; k < 64; ++k) {
            float wv = Ws[h][k];
            #pragma unroll
            for (int i = 0; i < 4; ++i)
                acc[i] += Xs[trow + i * 4][k] * wv;
        }
    }
    float bias = dt_bias[h];
    #pragma unroll
    for (int i = 0; i < 4; ++i) {
        float xv = acc[i] + bias;
        float sp = (xv > 20.f) ? xv : log1pf(expf(xv));
        dt_buf[(size_t)(t0 + trow + i * 4) * 64 + h] = sp;
    }
}

// ------------- per-(b,h) chunk-local inclusive cumsum of a=A*dt ----------
__global__ __launch_bounds__(256) void scan_kernel(const float* __restrict__ dt_buf,
                                                   const float* __restrict__ A_log,
                                                   float* __restrict__ acs) {
    int b = blockIdx.x >> 6, h = blockIdx.x & 63;
    float Ah = -expf(A_log[h]);
    __shared__ float s[256];
    int tid = threadIdx.x;
    for (int c = 0; c < NCH; ++c) {
        int t = b * LSEQ + c * LCH + tid;
        float a = Ah * dt_buf[t * 64 + h];
        s[tid] = a;
        __syncthreads();
        for (int off = 1; off < 256; off <<= 1) {
            float v = (tid >= off) ? s[tid - off] : 0.f;
            __syncthreads();
            s[tid] += v;
            __syncthreads();
        }
        acs[(size_t)blockIdx.x * LSEQ + c * LCH + tid] = s[tid];
        __syncthreads();
    }
}

// ---- convolved B/C (128 channels) in f32 --------------------------------
__global__ __launch_bounds__(128) void bcconv_kernel(const _Float16* __restrict__ cbuf,
                                                     const float* __restrict__ cw,
                                                     const float* __restrict__ cb,
                                                     float* __restrict__ bc) {
    int chl = threadIdx.x;
    int t = blockIdx.x;
    int b = t >> 11, lp = t & 2047;
    int ch = D_INNER + chl;
    float acc = cb[ch];
    #pragma unroll
    for (int j = 0; j < 4; ++j) {
        int lj = lp - 3 + j;
        if (lj >= 0)
            acc += cw[ch * 4 + j] * (float)cbuf[(size_t)(b * LSEQ + lj) * XBC_DIM + ch];
    }
    bc[(size_t)t * 128 + chl] = fsilu(acc);
}

// ===== MFMA chunk states =================================================
__global__ __launch_bounds__(256) void chunkstate_mfma(const _Float16* __restrict__ cbuf,
                                                       const float* __restrict__ bc,
                                                       const float* __restrict__ cw,
                                                       const float* __restrict__ cb,
                                                       const float* __restrict__ dt_buf,
                                                       const float* __restrict__ acs,
                                                       float* __restrict__ states) {
    const int h = blockIdx.x & 63;
    const int c = (blockIdx.x >> 6) & 7;
    const int b = blockIdx.x >> 9;
    const int tbase = b * LSEQ + c * LCH;
    const int tid = threadIdx.x, lane = tid & 63, w = tid >> 6;
    const int fr = lane & 15, fq = lane >> 4;

    __shared__ __align__(16) _Float16 XTw[64][XT_S];
    __shared__ __align__(16) _Float16 BT[64][XT_S];
    __shared__ float acs_s[256], dts[256];

    const float* acs_blk = acs + (size_t)(b * 64 + h) * LSEQ + c * LCH;
    acs_s[tid] = acs_blk[tid];
    dts[tid] = dt_buf[(size_t)(tbase + tid) * 64 + h];
    __syncthreads();
    const float acs_last = acs_s[LCH - 1];

    #pragma unroll 4
    for (int i = 0; i < 16; ++i) {
        int u = tid + i * 256;
        int s = u >> 4, pq = (u & 15) * 4;
        float wdec = fexp(acs_last - acs_s[s]) * dts[s];
        int lp = c * LCH + s;
        int ch0 = h * HD + pq;
        float tp[4][4];
        #pragma unroll
        for (int k = 0; k < 4; ++k)
            *(float4*)tp[k] = *(const float4*)(cw + (size_t)(ch0 + k) * 4);
        float a0 = cb[ch0], a1 = cb[ch0 + 1], a2 = cb[ch0 + 2], a3 = cb[ch0 + 3];
        #pragma unroll
        for (int j = 0; j < 4; ++j) {
            int lj = lp - 3 + j;
            if (lj >= 0) {
                float4 v = f16_ld4(cbuf, (size_t)(b * LSEQ + lj) * XBC_DIM + ch0);
                a0 += tp[0][j] * v.x; a1 += tp[1][j] * v.y;
                a2 += tp[2][j] * v.z; a3 += tp[3][j] * v.w;
            }
        }
        XTw[pq + 0][s] = (_Float16)(fsilu(a0) * wdec);
        XTw[pq + 1][s] = (_Float16)(fsilu(a1) * wdec);
        XTw[pq + 2][s] = (_Float16)(fsilu(a2) * wdec);
        XTw[pq + 3][s] = (_Float16)(fsilu(a3) * wdec);
    }
    #pragma unroll 4
    for (int i = 0; i < 16; ++i) {
        int u = tid + i * 256;
        int s = u >> 4, n4 = (u & 15) * 4;
        float4 v = *(const float4*)(bc + (size_t)(tbase + s) * 128 + n4);
        BT[n4 + 0][s] = (_Float16)v.x; BT[n4 + 1][s] = (_Float16)v.y;
        BT[n4 + 2][s] = (_Float16)v.z; BT[n4 + 3][s] = (_Float16)v.w;
    }
    __syncthreads();

    f4v acc[4];
    #pragma unroll
    for (int nf = 0; nf < 4; ++nf) acc[nf] = (f4v){0.f, 0.f, 0.f, 0.f};
    #pragma unroll
    for (int ks = 0; ks < 8; ++ks) {
        f16x8 af = *(const f16x8*)&XTw[w * 16 + fr][ks * 32 + fq * 8];
        #pragma unroll
        for (int nf = 0; nf < 4; ++nf) {
            f16x8 bf = *(const f16x8*)&BT[nf * 16 + fr][ks * 32 + fq * 8];
            acc[nf] = __builtin_amdgcn_mfma_f32_16x16x32_f16(af, bf, acc[nf], 0, 0, 0);
        }
    }
    float* sp = states + (size_t)blockIdx.x * 4096;
    #pragma unroll
    for (int nf = 0; nf < 4; ++nf)
        #pragma unroll
        for (int r = 0; r < 4; ++r)
            sp[(size_t)(w * 16 + fq * 4 + r) * 64 + nf * 16 + fr] = acc[nf][r];
}

// ----- inter-chunk recurrence per (b,h); in-place ------------------------
__global__ __launch_bounds__(256) void chunkscan_kernel(const float* __restrict__ acs,
                                                        float* __restrict__ states) {
    int b = blockIdx.x >> 6, h = blockIdx.x & 63;
    int tid = threadIdx.x;
    float4 S4[4];
    #pragma unroll
    for (int i = 0; i < 4; ++i) S4[i] = make_float4(0.f, 0.f, 0.f, 0.f);
    const float* acs_blk = acs + (size_t)blockIdx.x * LSEQ;
    for (int c = 0; c < NCH; ++c) {
        float d = expf(acs_blk[c * LCH + LCH - 1]);
        float4* sp = (float4*)(states + ((size_t)(b * NCH + c) * NH + h) * 4096 + tid * 16);
        float4 t4[4];
        #pragma unroll
        for (int i = 0; i < 4; ++i) t4[i] = sp[i];
        #pragma unroll
        for (int i = 0; i < 4; ++i) sp[i] = S4[i];
        #pragma unroll
        for (int i = 0; i < 4; ++i) {
            S4[i].x = d * S4[i].x + t4[i].x;
            S4[i].y = d * S4[i].y + t4[i].y;
            S4[i].z = d * S4[i].z + t4[i].z;
            S4[i].w = d * S4[i].w + t4[i].w;
        }
    }
}

// ===== MFMA ymerged: Y = Yoff + Ydiag + X·D; u = z·silu(Y), z/u f16 ======
__global__ __launch_bounds__(256) void ymerged_mfma(const _Float16* __restrict__ cbuf,
                                                    const float* __restrict__ bc,
                                                    const float* __restrict__ cw,
                                                    const float* __restrict__ cb,
                                                    _Float16* __restrict__ zf,
                                                    const float* __restrict__ dt_buf,
                                                    const float* __restrict__ acs,
                                                    const float* __restrict__ states,
                                                    const float* __restrict__ D_param,
                                                    float* __restrict__ usq) {
    const int h = blockIdx.x & 63;
    const int c = (blockIdx.x >> 6) & 7;
    const int b = blockIdx.x >> 9;
    const int tbase = b * LSEQ + c * LCH;
    const int tid = threadIdx.x, lane = tid & 63, w = tid >> 6;
    const int fr = lane & 15, fq = lane >> 4;

    __shared__ __align__(16) _Float16 XT[64][XT_S];
    __shared__ __align__(16) _Float16 Wl[4][64][WL_S];
    __shared__ float acs_s[256];
    __shared__ float dts[256];

    const float* acs_blk = acs + (size_t)(b * 64 + h) * LSEQ + c * LCH;
    acs_s[tid] = acs_blk[tid];
    dts[tid] = dt_buf[(size_t)(tbase + tid) * 64 + h];

    #pragma unroll 4
    for (int i = 0; i < 16; ++i) {
        int u = tid + i * 256;
        int s = u >> 4, pq = (u & 15) * 4;
        int lp = c * LCH + s;
        int ch0 = h * HD + pq;
        float tp[4][4];
        #pragma unroll
        for (int k = 0; k < 4; ++k)
            *(float4*)tp[k] = *(const float4*)(cw + (size_t)(ch0 + k) * 4);
        float a0 = cb[ch0], a1 = cb[ch0 + 1], a2 = cb[ch0 + 2], a3 = cb[ch0 + 3];
        #pragma unroll
        for (int j = 0; j < 4; ++j) {
            int lj = lp - 3 + j;
            if (lj >= 0) {
                float4 v = f16_ld4(cbuf, (size_t)(b * LSEQ + lj) * XBC_DIM + ch0);
                a0 += tp[0][j] * v.x; a1 += tp[1][j] * v.y;
                a2 += tp[2][j] * v.z; a3 += tp[3][j] * v.w;
            }
        }
        XT[pq + 0][s] = (_Float16)fsilu(a0);
        XT[pq + 1][s] = (_Float16)fsilu(a1);
        XT[pq + 2][s] = (_Float16)fsilu(a2);
        XT[pq + 3][s] = (_Float16)fsilu(a3);
    }
    __syncthreads();

    f16x8 cf[4][2];
    #pragma unroll
    for (int ls = 0; ls < 4; ++ls)
        #pragma unroll
        for (int kf = 0; kf < 2; ++kf) {
            const float* src = bc + (size_t)(tbase + w * 64 + ls * 16 + fr) * 128
                             + 64 + kf * 32 + fq * 8;
            cf[ls][kf] = cvt8(*(const float4*)src, *(const float4*)(src + 4));
        }

    float acsl[16];
    #pragma unroll
    for (int ls = 0; ls < 4; ++ls)
        #pragma unroll
        for (int r = 0; r < 4; ++r)
            acsl[ls * 4 + r] = acs_s[w * 64 + ls * 16 + fq * 4 + r];

    f4v Y[4][4];
    {
        f16x8 sf[4][2];
        #pragma unroll
        for (int ps = 0; ps < 4; ++ps)
            #pragma unroll
            for (int kf = 0; kf < 2; ++kf) {
                const float* src = states + (size_t)blockIdx.x * 4096
                                 + (ps * 16 + fr) * 64 + kf * 32 + fq * 8;
                sf[ps][kf] = cvt8(*(const float4*)src, *(const float4*)(src + 4));
            }
        f4v yo[4][4];
        #pragma unroll
        for (int ls = 0; ls < 4; ++ls)
            #pragma unroll
            for (int ps = 0; ps < 4; ++ps) {
                yo[ls][ps] = (f4v){0.f, 0.f, 0.f, 0.f};
                yo[ls][ps] = __builtin_amdgcn_mfma_f32_16x16x32_f16(cf[ls][0], sf[ps][0], yo[ls][ps], 0, 0, 0);
                yo[ls][ps] = __builtin_amdgcn_mfma_f32_16x16x32_f16(cf[ls][1], sf[ps][1], yo[ls][ps], 0, 0, 0);
            }
        #pragma unroll
        for (int ls = 0; ls < 4; ++ls)
            #pragma unroll
            for (int ps = 0; ps < 4; ++ps)
                #pragma unroll
                for (int r = 0; r < 4; ++r)
                    Y[ls][ps][r] = fexp(acsl[ls * 4 + r]) * yo[ls][ps][r];
    }

    for (int st = 0; st <= w; ++st) {
        f16x8 bf[4][2];
        #pragma unroll
        for (int ss = 0; ss < 4; ++ss)
            #pragma unroll
            for (int kf = 0; kf < 2; ++kf) {
                const float* src = bc + (size_t)(tbase + st * 64 + ss * 16 + fr) * 128
                                 + kf * 32 + fq * 8;
                bf[ss][kf] = cvt8(*(const float4*)src, *(const float4*)(src + 4));
            }
        f4v S[4][4];
        #pragma unroll
        for (int ls = 0; ls < 4; ++ls)
            #pragma unroll
            for (int ss = 0; ss < 4; ++ss) {
                S[ls][ss] = (f4v){0.f, 0.f, 0.f, 0.f};
                S[ls][ss] = __builtin_amdgcn_mfma_f32_16x16x32_f16(cf[ls][0], bf[ss][0], S[ls][ss], 0, 0, 0);
                S[ls][ss] = __builtin_amdgcn_mfma_f32_16x16x32_f16(cf[ls][1], bf[ss][1], S[ls][ss], 0, 0, 0);
            }
        #pragma unroll
        for (int ss = 0; ss < 4; ++ss) {
            int s_idx = st * 64 + ss * 16 + fr;
            float as = acs_s[s_idx];
            float dv = dts[s_idx];
            #pragma unroll
            for (int ls = 0; ls < 4; ++ls)
                #pragma unroll
                for (int r = 0; r < 4; ++r) {
                    int l_idx = w * 64 + ls * 16 + fq * 4 + r;
                    float wv = (s_idx <= l_idx)
                             ? fexp(acsl[ls * 4 + r] - as) * dv * S[ls][ss][r] : 0.f;
                    Wl[w][ls * 16 + fq * 4 + r][ss * 16 + fr] = (_Float16)wv;
                }
        }
        f16x8 wf[4][2], xf[4][2];
        #pragma unroll
        for (int ls = 0; ls < 4; ++ls)
            #pragma unroll
            for (int kf = 0; kf < 2; ++kf)
                wf[ls][kf] = *(const f16x8*)&Wl[w][ls * 16 + fr][kf * 32 + fq * 8];
        #pragma unroll
        for (int ps = 0; ps < 4; ++ps)
            #pragma unroll
            for (int kf = 0; kf < 2; ++kf)
                xf[ps][kf] = *(const f16x8*)&XT[ps * 16 + fr][st * 64 + kf * 32 + fq * 8];
        #pragma unroll
        for (int ls = 0; ls < 4; ++ls)
            #pragma unroll
            for (int ps = 0; ps < 4; ++ps) {
                Y[ls][ps] = __builtin_amdgcn_mfma_f32_16x16x32_f16(wf[ls][0], xf[ps][0], Y[ls][ps], 0, 0, 0);
                Y[ls][ps] = __builtin_amdgcn_mfma_f32_16x16x32_f16(wf[ls][1], xf[ps][1], Y[ls][ps], 0, 0, 0);
            }
    }

    float Dp = D_param[h];
    #pragma unroll
    for (int ls = 0; ls < 4; ++ls)
        #pragma unroll
        for (int r = 0; r < 4; ++r) {
            int l = w * 64 + ls * 16 + fq * 4 + r;
            int tl = tbase + l;
            float ss_acc = 0.f;
            #pragma unroll
            for (int ps = 0; ps < 4; ++ps) {
                int p = ps * 16 + fr;
                float y = Y[ls][ps][r] + (float)XT[p][l] * Dp;
                _Float16* zp = zf + (size_t)tl * D_INNER + h * HD + p;
                float uv = (float)(*zp) * fsilu(y);
                *zp = (_Float16)uv;
                ss_acc += uv * uv;
            }
            ss_acc += __shfl_xor(ss_acc, 1);
            ss_acc += __shfl_xor(ss_acc, 2);
            ss_acc += __shfl_xor(ss_acc, 4);
            ss_acc += __shfl_xor(ss_acc, 8);
            if (fr == 0) usq[(size_t)tl * 64 + h] = ss_acc;
        }
}

// ----- rstd[t] = rsqrt(mean(u^2) + eps) ----------------------------------
__global__ __launch_bounds__(256) void rstd_kernel(const float* __restrict__ usq,
                                                   float* __restrict__ rstd) {
    int t = blockIdx.x * 256 + threadIdx.x;
    float s = 0.f;
    #pragma unroll
    for (int i = 0; i < 16; ++i) {
        float4 v = *(const float4*)(usq + (size_t)t * 64 + i * 4);
        s += v.x + v.y + v.z + v.w;
    }
    rstd[t] = rsqrtf(s / 4096.f + EPS_R);
}

extern "C" void kernel_launch(void* const* d_in, const int* in_sizes, int n_in,
                              void* d_out, int out_size, void* d_ws, size_t ws_size,
                              hipStream_t stream) {
    const float* x        = (const float*)d_in[0];
    const float* w_in     = (const float*)d_in[1];
    const float* conv_w   = (const float*)d_in[2];
    const float* conv_b   = (const float*)d_in[3];
    const float* dt_bias  = (const float*)d_in[4];
    const float* A_log    = (const float*)d_in[5];
    const float* D_param  = (const float*)d_in[6];
    const float* norm_w   = (const float*)d_in[7];
    const float* w_out    = (const float*)d_in[8];
    float* out = (float*)d_out;

    const size_t sz_zf  = (size_t)TTOK * D_INNER * 2;
    const size_t sz_cb  = (size_t)TTOK * XBC_DIM * 2;
    const size_t sz_x16 = (size_t)TTOK * D_MODEL * 2;
    const size_t sz_wi  = (size_t)N_ZX * D_MODEL * 2;
    const size_t sz_wo  = (size_t)D_MODEL * D_INNER * 2;
    const size_t sz_bc  = (size_t)TTOK * 128 * 4;
    const size_t sz_dt  = (size_t)TTOK * 64 * 4;
    const size_t sz_acs = (size_t)128 * LSEQ * 4;
    const size_t sz_st  = (size_t)1024 * 4096 * 4;
    const size_t need = sz_zf + sz_cb + sz_x16 + sz_wi + sz_wo
                      + sz_bc + sz_dt + sz_acs + sz_st;   // 156,762,112
    if (ws_size < need) return;

    char* p = (char*)d_ws;
    _Float16* zf     = (_Float16*)p; p += sz_zf;
    _Float16* cbuf   = (_Float16*)p; p += sz_cb;
    _Float16* x16    = (_Float16*)p; p += sz_x16;
    _Float16* win16  = (_Float16*)p; p += sz_wi;
    _Float16* wout16 = (_Float16*)p; p += sz_wo;
    float*    bc     = (float*)p;    p += sz_bc;
    float*    dtb    = (float*)p;    p += sz_dt;
    float*    acs    = (float*)p;    p += sz_acs;
    float*    states = (float*)p;    p += sz_st;
    float* usq  = dtb;
    float* rstd = acs;

    cvt16_kernel<<<(TTOK * D_MODEL / 8 + 255) / 256, 256, 0, stream>>>(
        x, x16, (size_t)TTOK * D_MODEL / 8);
    cvt16_kernel<<<((size_t)N_ZX * D_MODEL / 8 + 255) / 256, 256, 0, stream>>>(
        w_in, win16, (size_t)N_ZX * D_MODEL / 8);
    cvt_wout_kernel<<<(D_MODEL * D_INNER / 8 + 255) / 256, 256, 0, stream>>>(
        w_out, norm_w, wout16);

    gemm_in16<<<(N_ZX / 128) * (TTOK / 128), 256, 0, stream>>>(x16, win16, zf, cbuf);
    dtproj_kernel<<<TTOK / 16, 256, 0, stream>>>(x, w_in, dt_bias, dtb);
    scan_kernel<<<2 * NH, 256, 0, stream>>>(dtb, A_log, acs);
    bcconv_kernel<<<TTOK, 128, 0, stream>>>(cbuf, conv_w, conv_b, bc);
    chunkstate_mfma<<<2 * NCH * NH, 256, 0, stream>>>(
        cbuf, bc, conv_w, conv_b, dtb, acs, states);
    chunkscan_kernel<<<2 * NH, 256, 0, stream>>>(acs, states);
    ymerged_mfma<<<2 * NCH * NH, 256, 0, stream>>>(
        cbuf, bc, conv_w, conv_b, zf, dtb, acs, states, D_param, usq);
    rstd_kernel<<<TTOK / 256, 256, 0, stream>>>(usq, rstd);
    gemm_out16<<<(D_MODEL / 128) * (TTOK / 128), 256, 0, stream>>>(zf, wout16, out, rstd);
}